// Round 8
// baseline (420.574 us; speedup 1.0000x reference)
//
#include <hip/hip_runtime.h>
#include <math.h>

#define NROWS 65536
#define DIM 256
#define KC 1024
#define FCAP1 16384
#define FCAP2 4096
#define MARGIN1 0.024f
#define MARGIN2 5.0e-5f

typedef float  floatx4 __attribute__((ext_vector_type(4)));
typedef short  shortx8 __attribute__((ext_vector_type(8)));

__device__ __forceinline__ unsigned short f2bf(float f) {
    unsigned u = __float_as_uint(f);
    return (unsigned short)((u + 0x7fffu + ((u >> 16) & 1u)) >> 16);
}
__device__ __forceinline__ float bf2f(unsigned short h) {
    return __uint_as_float(((unsigned)h) << 16);
}
// monotone float->u32 mapping (works for negatives)
__device__ __forceinline__ unsigned fmap(float s) {
    unsigned u = __float_as_uint(s);
    return u ^ (unsigned)(((int)u >> 31) | 0x80000000);
}
__device__ __forceinline__ float funmap(unsigned m) {
    unsigned u = (m & 0x80000000u) ? (m ^ 0x80000000u) : ~m;
    return __uint_as_float(u);
}
#define UMIN(a, b) ((a) < (b) ? (a) : (b))

// Fragment-ordered E layout: for MFMA tile ct (32 codes), k-slice kt, half h
// (codes ct*32+h*16+0..15), the 64-lane B-fragment is contiguous:
//   half_idx(ct,kt,h, lane, el) = ct*8192 + (kt*2+h)*512 + lane*8 + el
// lane = l4*16+l15 holds code ct*32+h*16+l15, dims kt*32+l4*8+el.
// Tile ct = 8192 halfs = 16 KB contiguous -> linear LDS staging, and lane l
// reads byte l*16 of each 1KB fragment (conflict-free ds_read_b128).

// ---------------------------------------------------------------------------
// Kernel 1: E-only preprocessing. E row norms (en); E -> hi/lo bf16 split
// written in FRAGMENT ORDER (EbFH/EbFL); zero accum + counters (incl. the
// gather completion counter flagCnt[2]).
// ---------------------------------------------------------------------------
__global__ void __launch_bounds__(256) vq_norms(const float* __restrict__ e,
                                                float* __restrict__ en,
                                                unsigned short* __restrict__ EbFH,
                                                unsigned short* __restrict__ EbFL,
                                                float* __restrict__ accum,
                                                int* __restrict__ flagCnt) {
    if (blockIdx.x == 0 && threadIdx.x == 0) {
        *accum = 0.0f; flagCnt[0] = 0; flagCnt[1] = 0; flagCnt[2] = 0;
    }
    const int wave = threadIdx.x >> 6;
    const int lane = threadIdx.x & 63;
    const int er = blockIdx.x * 4 + wave;   // grid = KC/4 exactly
    float4 v = ((const float4*)(e + (size_t)er * DIM))[lane];
    ushort4 oh, ol;
    oh.x = f2bf(v.x); ol.x = f2bf(v.x - bf2f(oh.x));
    oh.y = f2bf(v.y); ol.y = f2bf(v.y - bf2f(oh.y));
    oh.z = f2bf(v.z); ol.z = f2bf(v.z - bf2f(oh.z));
    oh.w = f2bf(v.w); ol.w = f2bf(v.w - bf2f(oh.w));
    {   // fragment-order scatter: this lane holds dims lane*4 .. lane*4+3
        const int ct  = er >> 5;
        const int l15 = er & 15;
        const int hf  = (er >> 4) & 1;
        const int kt  = lane >> 3;          // (lane*4)>>5
        const int l4  = (lane >> 1) & 3;    // ((lane*4)>>3)&3
        const int el  = (lane & 1) * 4;     // (lane*4)&7
        const size_t idx = (size_t)ct * 8192 + (kt * 2 + hf) * 512
                         + (l4 * 16 + l15) * 8 + el;
        *(ushort4*)(EbFH + idx) = oh;
        *(ushort4*)(EbFL + idx) = ol;
    }
    float s = (v.x * v.x + v.y * v.y) + (v.z * v.z + v.w * v.w);
#pragma unroll
    for (int off = 1; off < 64; off <<= 1)
        s += __shfl_xor(s, off, 64);
    if (lane == 0) en[er] = s;
}

// ---------------------------------------------------------------------------
// Kernel 2 (pass1): bf16 MFMA distance-GEMM + top-2 argmin, full codebook.
// R12 = R1's SHAPE x R7's LAYOUT (first time combined):
//  - 512 blocks x 4 waves = 2 independent blocks/CU: when one block's waves
//    drain at the per-tile barrier, the other block's MFMAs fill the CU
//    (the cross-block overlap that made R1@69us beat every 1-block/CU
//    variant at 77-91us).
//  - fragment-ordered LDS tile (R7): staging is a linear coalesced 64B/thread
//    copy; ds_read_b128 at byte l*16 of a contiguous 1KB fragment is
//    conflict-free (R1's padded row-major layout cost 4.19M conflict cycles).
//  - float top-2 inline update, packed + MARGIN1 flags written directly.
// Scores bit-identical to R1/R6/R7 (same bf16 values, same MFMA order).
// ---------------------------------------------------------------------------
__global__ void __launch_bounds__(256) vq_pass1(const float* __restrict__ X,
                                                const unsigned short* __restrict__ EbFH,
                                                const float* __restrict__ en,
                                                unsigned long long* __restrict__ packed,
                                                int* __restrict__ flagCnt,
                                                int* __restrict__ flagList1) {
    __shared__ unsigned short Bs[2][8192];   // 2 x 16KB fragment-ordered tile

    const int tid = threadIdx.x;
    const int w   = tid >> 6;      // wave 0..3
    const int l   = tid & 63;
    const int l4  = l >> 4;        // quad 0..3
    const int l15 = l & 15;
    const int rowBase = blockIdx.x * 128;
    const int waveRow = rowBase + w * 32;

    shortx8 A[2][8];
#pragma unroll
    for (int mt = 0; mt < 2; mt++) {
        const float* xp = X + (size_t)(waveRow + mt * 16 + l15) * DIM + l4 * 8;
#pragma unroll
        for (int kt = 0; kt < 8; kt++) {
            float4 p = *(const float4*)(xp + kt * 32);
            float4 q = *(const float4*)(xp + kt * 32 + 4);
            shortx8 v;
            v[0] = (short)f2bf(p.x); v[1] = (short)f2bf(p.y);
            v[2] = (short)f2bf(p.z); v[3] = (short)f2bf(p.w);
            v[4] = (short)f2bf(q.x); v[5] = (short)f2bf(q.y);
            v[6] = (short)f2bf(q.z); v[7] = (short)f2bf(q.w);
            A[mt][kt] = v;
        }
    }

    uint4 s0, s1, s2, s3;
    {   // prologue: stage tile 0 into buf 0 (linear: thread tid -> 64B)
        const uint4* src = (const uint4*)(EbFH + (size_t)tid * 32);
        s0 = src[0]; s1 = src[1]; s2 = src[2]; s3 = src[3];
        uint4* dst = (uint4*)&Bs[0][tid * 32];
        dst[0] = s0; dst[1] = s1; dst[2] = s2; dst[3] = s3;
    }

    float bs1[8], bs2[8];
    unsigned bc[8];
#pragma unroll
    for (int i = 0; i < 8; i++) { bs1[i] = 3.0e38f; bs2[i] = 3.0e38f; bc[i] = 0; }

    for (int ct = 0; ct < 32; ct++) {
        const int cur = ct & 1, nxt = cur ^ 1;
        __syncthreads();
        bool doNext = (ct + 1 < 32);
        if (doNext) {   // issue next-tile loads BEFORE compute (latency hides)
            const uint4* src = (const uint4*)(EbFH + (size_t)(ct + 1) * 8192 + tid * 32);
            s0 = src[0]; s1 = src[1]; s2 = src[2]; s3 = src[3];
        }
        float en0 = en[ct * 32 + l15];
        float en1 = en[ct * 32 + 16 + l15];

        floatx4 acc[2][2];
#pragma unroll
        for (int mt = 0; mt < 2; mt++)
#pragma unroll
            for (int nt = 0; nt < 2; nt++)
                acc[mt][nt] = (floatx4){0.f, 0.f, 0.f, 0.f};

#pragma unroll
        for (int kt = 0; kt < 8; kt++) {
            shortx8 b0 = *(const shortx8*)&Bs[cur][(kt * 2 + 0) * 512 + l * 8];
            shortx8 b1 = *(const shortx8*)&Bs[cur][(kt * 2 + 1) * 512 + l * 8];
            acc[0][0] = __builtin_amdgcn_mfma_f32_16x16x32_bf16(A[0][kt], b0, acc[0][0], 0, 0, 0);
            acc[0][1] = __builtin_amdgcn_mfma_f32_16x16x32_bf16(A[0][kt], b1, acc[0][1], 0, 0, 0);
            acc[1][0] = __builtin_amdgcn_mfma_f32_16x16x32_bf16(A[1][kt], b0, acc[1][0], 0, 0, 0);
            acc[1][1] = __builtin_amdgcn_mfma_f32_16x16x32_bf16(A[1][kt], b1, acc[1][1], 0, 0, 0);
        }

        {   // inline float top-2 update
            unsigned cb = (unsigned)(ct * 32 + l15);
#pragma unroll
            for (int mt = 0; mt < 2; mt++)
#pragma unroll
                for (int r = 0; r < 4; r++) {
                    float s0f = fmaf(-2.0f, acc[mt][0][r], en0);
                    float s1f = fmaf(-2.0f, acc[mt][1][r], en1);
                    float lo = fminf(s0f, s1f);
                    float hi = fmaxf(s0f, s1f);
                    unsigned cLo = (s1f < s0f) ? (cb + 16u) : cb;
                    int sl = mt * 4 + r;
                    float disp = fmaxf(bs1[sl], lo);
                    bs2[sl] = fminf(fminf(bs2[sl], hi), disp);
                    bc[sl]  = (lo < bs1[sl]) ? cLo : bc[sl];
                    bs1[sl] = fminf(bs1[sl], lo);
                }
        }

        if (doNext) {   // land the staged regs into the other buffer
            uint4* dst = (uint4*)&Bs[nxt][tid * 32];
            dst[0] = s0; dst[1] = s1; dst[2] = s2; dst[3] = s3;
        }
    }

    // ---- butterfly top-2 merge across l15; lane l15==0 writes results.
    // Cross-lane tie order differs from first-index, but ties => gap 0 <
    // MARGIN1 => flagged => pass2/pass3 re-solve exactly.
#pragma unroll
    for (int sl = 0; sl < 8; sl++) {
        float b1 = bs1[sl], b2 = bs2[sl];
        unsigned c = bc[sl];
#pragma unroll
        for (int m = 1; m < 16; m <<= 1) {
            float ob1 = __shfl_xor(b1, m, 64);
            float ob2 = __shfl_xor(b2, m, 64);
            unsigned oc = (unsigned)__shfl_xor((int)c, m, 64);
            float nb2 = fminf(fmaxf(b1, ob1), fminf(b2, ob2));
            bool take = ob1 < b1;
            b1 = take ? ob1 : b1;
            c  = take ? oc : c;
            b2 = nb2;
        }
        if (l15 == 0) {
            int mt = sl >> 2, r = sl & 3;
            int row = waveRow + mt * 16 + l4 * 4 + r;
            packed[row] = ((unsigned long long)fmap(b1) << 32) | c;
            if (b2 - b1 < MARGIN1) {
                int pos = atomicAdd(&flagCnt[0], 1);
                if (pos < FCAP1) flagList1[pos] = row;
            }
        }
    }
}

// ---------------------------------------------------------------------------
// Kernel 3 (pass2): 3-product bf16-split MFMA (xh*eh + xh*el + xl*eh) on
// pass1-flagged rows only. 32 rows/block, code dim split across the 4
// waves, no LDS staging / no main-loop barriers. B fragments read from
// fragment-ordered EbFH/EbFL (coalesced, L2-resident).
// Cross-wave top-2 merged through LDS epilogue; code sets disjoint across
// waves so the packed-u64 merge is exact.
// ---------------------------------------------------------------------------
__global__ void __launch_bounds__(256) vq_pass2(const float* __restrict__ X,
                                                const unsigned short* __restrict__ EbFH,
                                                const unsigned short* __restrict__ EbFL,
                                                const float* __restrict__ en,
                                                unsigned long long* __restrict__ packed,
                                                int* __restrict__ flagCnt,
                                                const int* __restrict__ flagList1,
                                                int* __restrict__ flagList2) {
    __shared__ unsigned long long V[4][32][16];   // 16 KB
    __shared__ unsigned W[4][32][16];             //  8 KB

    int cnt = flagCnt[0];
    if (cnt > FCAP1) cnt = FCAP1;
    const int base = blockIdx.x * 32;
    if (base >= cnt) return;

    const int tid = threadIdx.x;
    const int w = tid >> 6, l = tid & 63;
    const int l4 = l >> 4, l15 = l & 15;

    // ---- A preload (hi+lo) via row indirection; same 32 rows for all waves
    shortx8 Ah[2][8], Al[2][8];
#pragma unroll
    for (int mt = 0; mt < 2; mt++) {
        int j = base + mt * 16 + l15;
        int row = flagList1[j < cnt ? j : cnt - 1];
        const float* xp = X + (size_t)row * DIM + l4 * 8;
#pragma unroll
        for (int kt = 0; kt < 8; kt++) {
            shortx8 vh, vl;
#pragma unroll
            for (int c4 = 0; c4 < 2; c4++) {
                float4 p = *(const float4*)(xp + kt * 32 + c4 * 4);
                float f[4] = {p.x, p.y, p.z, p.w};
#pragma unroll
                for (int q = 0; q < 4; q++) {
                    unsigned short h = f2bf(f[q]);
                    vh[c4 * 4 + q] = (short)h;
                    vl[c4 * 4 + q] = (short)f2bf(f[q] - bf2f(h));
                }
            }
            Ah[mt][kt] = vh; Al[mt][kt] = vl;
        }
    }

    unsigned long long best[8];
    unsigned bsec[8];
#pragma unroll
    for (int i = 0; i < 8; i++) { best[i] = ~0ull; bsec[i] = 0xFFFFFFFFu; }

    // wave w covers codes [w*256, (w+1)*256): tiles ct = w*8 .. w*8+7
    for (int t = 0; t < 8; t++) {
        const int ct = w * 8 + t;
        const unsigned short* fbh = EbFH + (size_t)ct * 8192 + l * 8;
        const unsigned short* fbl = EbFL + (size_t)ct * 8192 + l * 8;
        float en0 = en[ct * 32 + l15];
        float en1 = en[ct * 32 + 16 + l15];

        floatx4 acc[2][2];
#pragma unroll
        for (int mt = 0; mt < 2; mt++)
#pragma unroll
            for (int nt = 0; nt < 2; nt++)
                acc[mt][nt] = (floatx4){0.f, 0.f, 0.f, 0.f};

#pragma unroll
        for (int kt = 0; kt < 8; kt++) {
            shortx8 bh0 = *(const shortx8*)(fbh + (kt * 2 + 0) * 512);
            shortx8 bh1 = *(const shortx8*)(fbh + (kt * 2 + 1) * 512);
            shortx8 bl0 = *(const shortx8*)(fbl + (kt * 2 + 0) * 512);
            shortx8 bl1 = *(const shortx8*)(fbl + (kt * 2 + 1) * 512);
#pragma unroll
            for (int mt = 0; mt < 2; mt++) {
                acc[mt][0] = __builtin_amdgcn_mfma_f32_16x16x32_bf16(Ah[mt][kt], bh0, acc[mt][0], 0, 0, 0);
                acc[mt][0] = __builtin_amdgcn_mfma_f32_16x16x32_bf16(Ah[mt][kt], bl0, acc[mt][0], 0, 0, 0);
                acc[mt][0] = __builtin_amdgcn_mfma_f32_16x16x32_bf16(Al[mt][kt], bh0, acc[mt][0], 0, 0, 0);
                acc[mt][1] = __builtin_amdgcn_mfma_f32_16x16x32_bf16(Ah[mt][kt], bh1, acc[mt][1], 0, 0, 0);
                acc[mt][1] = __builtin_amdgcn_mfma_f32_16x16x32_bf16(Ah[mt][kt], bl1, acc[mt][1], 0, 0, 0);
                acc[mt][1] = __builtin_amdgcn_mfma_f32_16x16x32_bf16(Al[mt][kt], bh1, acc[mt][1], 0, 0, 0);
            }
        }

#pragma unroll
        for (int mt = 0; mt < 2; mt++)
#pragma unroll
            for (int nt = 0; nt < 2; nt++) {
                float enc = nt ? en1 : en0;
                unsigned code = (unsigned)(ct * 32 + nt * 16 + l15);
#pragma unroll
                for (int r = 0; r < 4; r++) {
                    float s = fmaf(-2.0f, acc[mt][nt][r], enc);
                    unsigned m = fmap(s);
                    unsigned long long p = ((unsigned long long)m << 32) | code;
                    int sl = mt * 4 + r;
                    if (p < best[sl]) {
                        bsec[sl] = UMIN(bsec[sl], (unsigned)(best[sl] >> 32));
                        best[sl] = p;
                    } else {
                        bsec[sl] = UMIN(bsec[sl], m);
                    }
                }
            }
    }

    // ---- cross-wave top-2 merge (code sets disjoint across waves)
#pragma unroll
    for (int sl = 0; sl < 8; sl++) {
        int mt = sl >> 2, r = sl & 3;
        int rl = mt * 16 + l4 * 4 + r;   // row-in-block 0..31
        V[w][rl][l15] = best[sl];
        W[w][rl][l15] = bsec[sl];
    }
    __syncthreads();
    if (tid < 32 && base + tid < cnt) {
        unsigned long long b1 = ~0ull;
        unsigned b2 = 0xFFFFFFFFu;
#pragma unroll
        for (int ww = 0; ww < 4; ww++) {
#pragma unroll
            for (int i = 0; i < 16; i++) {
                unsigned long long v = V[ww][tid][i];
                unsigned wv = W[ww][tid][i];
                if (v < b1) {
                    b2 = UMIN(b2, (unsigned)(b1 >> 32));
                    b1 = v;
                    b2 = UMIN(b2, wv);
                } else {
                    b2 = UMIN(b2, (unsigned)(v >> 32));
                }
            }
        }
        int row = flagList1[base + tid];
        packed[row] = b1;
        float s1 = funmap((unsigned)(b1 >> 32));
        float s2 = funmap(b2);
        if (s2 - s1 < MARGIN2) {
            int pos = atomicAdd(&flagCnt[1], 1);
            if (pos < FCAP2) flagList2[pos] = row;
        }
    }
}

// ---------------------------------------------------------------------------
// Kernel 4 (pass3): exact fp32 re-solve for pass2-flagged rows (~O(10)).
// xn recomputed in-kernel with the bit-identical partial-sum + xor-butterfly
// + lane-0 broadcast. Threads 0..63 run the IDENTICAL sequential-d fmaf
// chain (same summation order -> same winners), same np-rounded score,
// packed-u64 first-index ties.
// ---------------------------------------------------------------------------
__global__ void __launch_bounds__(256) vq_pass3(const float* __restrict__ X,
                                                const float* __restrict__ E,
                                                const float* __restrict__ en,
                                                unsigned long long* __restrict__ packed,
                                                const int* __restrict__ flagCnt2,
                                                const int* __restrict__ flagList2) {
    __shared__ float Et[64][257];   // 64 codes x 256 dims, +1 pad
    __shared__ float xs[256];
    __shared__ unsigned long long red[64];
    int cnt = *flagCnt2;
    if (cnt > FCAP2) cnt = FCAP2;
    const int tid = threadIdx.x;

    for (int it = blockIdx.x; it < cnt; it += gridDim.x) {
        int row = flagList2[it];
        __syncthreads();   // protect xs/red reuse across it-iterations
        float xnr = 0.0f;
        if (tid < 64) {
            float4 xv = *(const float4*)&X[(size_t)row * DIM + tid * 4];
            *(float4*)&xs[tid * 4] = xv;
            float s = (xv.x * xv.x + xv.y * xv.y) + (xv.z * xv.z + xv.w * xv.w);
#pragma unroll
            for (int off = 1; off < 64; off <<= 1)
                s += __shfl_xor(s, off, 64);
            xnr = __shfl(s, 0, 64);   // lane-0 value == old xn[row] bit-exact
        }
        unsigned long long bl = ~0ull;
        for (int t = 0; t < KC / 64; t++) {
            __syncthreads();
            {   // flat-coalesced tile load: 64 codes x 256 f32 = 4096 float4
                int f4 = tid;               // + 256*q
#pragma unroll
                for (int q = 0; q < 16; q++, f4 += 256) {
                    int code = f4 >> 6;     // 64 float4 per row
                    int off4 = f4 & 63;
                    *(float4*)&Et[code][off4 * 4] =
                        *(const float4*)(E + ((size_t)(t * 64 + code) * DIM) + off4 * 4);
                }
            }
            __syncthreads();
            if (tid < 64) {
                int c = t * 64 + tid;
                const float* er = Et[tid];
                float dot = 0.0f;
#pragma unroll
                for (int d = 0; d < 256; d += 4) {
                    dot = fmaf(xs[d + 0], er[d + 0], dot);
                    dot = fmaf(xs[d + 1], er[d + 1], dot);
                    dot = fmaf(xs[d + 2], er[d + 2], dot);
                    dot = fmaf(xs[d + 3], er[d + 3], dot);
                }
                float s = fmaf(-2.0f, dot, xnr + en[c]);   // matches np rounding
                unsigned long long p =
                    ((unsigned long long)__float_as_uint(s) << 32) | (unsigned)c;
                if (p < bl) bl = p;
            }
        }
        if (tid < 64) red[tid] = bl;
        __syncthreads();
        if (tid == 0) {
            unsigned long long m = red[0];
#pragma unroll
            for (int i = 1; i < 64; i++)
                if (red[i] < m) m = red[i];
            packed[row] = m;
        }
    }
}

// ---------------------------------------------------------------------------
// Kernel 5: gather quantized rows + fused squared-diff partial sums.
// R12: finalize folded in -- the LAST block (completion counter flagCnt[2])
// reads the total via atomicAdd(accum, 0.0f) (coherent atomic path, no
// stale-L2 risk) and writes the loss scalar. vq_finalize kernel deleted.
// ---------------------------------------------------------------------------
__global__ void __launch_bounds__(256) vq_gather(const float* __restrict__ X,
                                                 const float* __restrict__ E,
                                                 const unsigned long long* __restrict__ packed,
                                                 float* __restrict__ out,
                                                 float* __restrict__ accum,
                                                 int* __restrict__ done) {
    const int tid = threadIdx.x;
    const int wave = tid >> 6;
    const int lane = tid & 63;
    const size_t rowBase = (size_t)blockIdx.x * 16;
    float part = 0.0f;
#pragma unroll
    for (int rr = 0; rr < 4; rr++) {
        size_t row = rowBase + wave + rr * 4;
        int code = (int)(unsigned int)(packed[row] & 0xffffffffull);
        float4 q = ((const float4*)(E + (size_t)code * DIM))[lane];
        float4 xv = ((const float4*)(X + row * DIM))[lane];
        ((float4*)(out + row * DIM))[lane] = q;
        float dx = q.x - xv.x, dy = q.y - xv.y, dz = q.z - xv.z, dw = q.w - xv.w;
        part = fmaf(dx, dx, part);
        part = fmaf(dy, dy, part);
        part = fmaf(dz, dz, part);
        part = fmaf(dw, dw, part);
    }
#pragma unroll
    for (int off = 1; off < 64; off <<= 1)
        part += __shfl_xor(part, off, 64);
    __shared__ float red[4];
    if ((tid & 63) == 0) red[tid >> 6] = part;
    __syncthreads();
    if (tid == 0) {
        float s = (red[0] + red[1]) + (red[2] + red[3]);
        atomicAdd(accum, s);
        __threadfence();
        int old = atomicAdd(done, 1);
        if (old == (int)gridDim.x - 1) {
            float total = atomicAdd(accum, 0.0f);   // coherent readback
            float m = total * (1.0f / 16777216.0f); // mean = sum / 2^24 exact
            out[(size_t)NROWS * DIM] = m + m;
        }
    }
}

extern "C" void kernel_launch(void* const* d_in, const int* in_sizes, int n_in,
                              void* d_out, int out_size, void* d_ws, size_t ws_size,
                              hipStream_t stream) {
    const float* X = (const float*)d_in[0];   // [65536, 256]
    const float* E = (const float*)d_in[1];   // [1024, 256]
    float* out = (float*)d_out;               // quantized [65536*256] + loss [1]

    char* ws = (char*)d_ws;
    float* en = (float*)ws;                                           //    4096 B
    unsigned short* EbFH = (unsigned short*)(ws + 4096);              //  524288 B
    unsigned short* EbFL = (unsigned short*)(ws + 528384);            //  524288 B
    unsigned long long* packed = (unsigned long long*)(ws + 1052672); //  524288 B
    int* flagList1 = (int*)(ws + 1576960);                            //   65536 B
    int* flagList2 = (int*)(ws + 1642496);                            //   16384 B
    float* accum = (float*)(ws + 1658880);
    int* flagCnt = (int*)(ws + 1658884);                              // [cnt1, cnt2, done]

    vq_norms   <<<KC / 4, 256, 0, stream>>>(E, en, EbFH, EbFL, accum, flagCnt);
    vq_pass1   <<<NROWS / 128, 256, 0, stream>>>(X, EbFH, en, packed, flagCnt, flagList1);
    vq_pass2   <<<FCAP1 / 32, 256, 0, stream>>>(X, EbFH, EbFL, en, packed, flagCnt, flagList1, flagList2);
    vq_pass3   <<<64, 256, 0, stream>>>(X, E, en, packed, flagCnt + 1, flagList2);
    vq_gather  <<<NROWS / 16, 256, 0, stream>>>(X, E, packed, out, accum, flagCnt + 2);
}

// Round 9
// 315.004 us; speedup vs baseline: 1.3351x; 1.3351x over previous
//
#include <hip/hip_runtime.h>
#include <math.h>

#define NROWS 65536
#define DIM 256
#define KC 1024
#define FCAP1 16384
#define FCAP2 4096
#define MARGIN1 0.024f
#define MARGIN2 5.0e-5f

typedef float  floatx4 __attribute__((ext_vector_type(4)));
typedef short  shortx8 __attribute__((ext_vector_type(8)));

__device__ __forceinline__ unsigned short f2bf(float f) {
    unsigned u = __float_as_uint(f);
    return (unsigned short)((u + 0x7fffu + ((u >> 16) & 1u)) >> 16);
}
__device__ __forceinline__ float bf2f(unsigned short h) {
    return __uint_as_float(((unsigned)h) << 16);
}
// monotone float->u32 mapping (works for negatives)
__device__ __forceinline__ unsigned fmap(float s) {
    unsigned u = __float_as_uint(s);
    return u ^ (unsigned)(((int)u >> 31) | 0x80000000);
}
__device__ __forceinline__ float funmap(unsigned m) {
    unsigned u = (m & 0x80000000u) ? (m ^ 0x80000000u) : ~m;
    return __uint_as_float(u);
}
#define UMIN(a, b) ((a) < (b) ? (a) : (b))

// Fragment-ordered E layout: for MFMA tile ct (32 codes), k-slice kt, half h
// (codes ct*32+h*16+0..15), the 64-lane B-fragment is contiguous:
//   half_idx(ct,kt,h, lane, el) = ct*8192 + (kt*2+h)*512 + lane*8 + el
// lane = l4*16+l15 holds code ct*32+h*16+l15, dims kt*32+l4*8+el.
// Tile ct = 8192 halfs = 16 KB contiguous -> linear LDS staging, and lane l
// reads byte l*16 of each 1KB fragment (conflict-free ds_read_b128).

// ---------------------------------------------------------------------------
// Kernel 1: E-only preprocessing. E row norms (en); E -> hi/lo bf16 split
// written in FRAGMENT ORDER (EbFH/EbFL); zero accum + counters.
// ---------------------------------------------------------------------------
__global__ void __launch_bounds__(256) vq_norms(const float* __restrict__ e,
                                                float* __restrict__ en,
                                                unsigned short* __restrict__ EbFH,
                                                unsigned short* __restrict__ EbFL,
                                                float* __restrict__ accum,
                                                int* __restrict__ flagCnt) {
    if (blockIdx.x == 0 && threadIdx.x == 0) {
        *accum = 0.0f; flagCnt[0] = 0; flagCnt[1] = 0;
    }
    const int wave = threadIdx.x >> 6;
    const int lane = threadIdx.x & 63;
    const int er = blockIdx.x * 4 + wave;   // grid = KC/4 exactly
    float4 v = ((const float4*)(e + (size_t)er * DIM))[lane];
    ushort4 oh, ol;
    oh.x = f2bf(v.x); ol.x = f2bf(v.x - bf2f(oh.x));
    oh.y = f2bf(v.y); ol.y = f2bf(v.y - bf2f(oh.y));
    oh.z = f2bf(v.z); ol.z = f2bf(v.z - bf2f(oh.z));
    oh.w = f2bf(v.w); ol.w = f2bf(v.w - bf2f(oh.w));
    {   // fragment-order scatter: this lane holds dims lane*4 .. lane*4+3
        const int ct  = er >> 5;
        const int l15 = er & 15;
        const int hf  = (er >> 4) & 1;
        const int kt  = lane >> 3;          // (lane*4)>>5
        const int l4  = (lane >> 1) & 3;    // ((lane*4)>>3)&3
        const int el  = (lane & 1) * 4;     // (lane*4)&7
        const size_t idx = (size_t)ct * 8192 + (kt * 2 + hf) * 512
                         + (l4 * 16 + l15) * 8 + el;
        *(ushort4*)(EbFH + idx) = oh;
        *(ushort4*)(EbFL + idx) = ol;
    }
    float s = (v.x * v.x + v.y * v.y) + (v.z * v.z + v.w * v.w);
#pragma unroll
    for (int off = 1; off < 64; off <<= 1)
        s += __shfl_xor(s, off, 64);
    if (lane == 0) en[er] = s;
}

// ---------------------------------------------------------------------------
// Kernel 2 (pass1): bf16 MFMA distance-GEMM + top-2 argmin, full codebook.
// R12 (kept unchanged in R13 for a clean counter read):
//  - 512 blocks x 4 waves = 2 independent blocks/CU: cross-block overlap at
//    the per-tile barrier (R1's winning shape).
//  - fragment-ordered LDS tile (R7 layout): staging is a linear coalesced
//    64B/thread copy; ds_read_b128 at byte l*16 of a contiguous 1KB
//    fragment is conflict-free.
//  - float top-2 inline update, packed + MARGIN1 flags written directly.
// Scores bit-identical to R1/R6/R7 (same bf16 values, same MFMA order).
// ---------------------------------------------------------------------------
__global__ void __launch_bounds__(256) vq_pass1(const float* __restrict__ X,
                                                const unsigned short* __restrict__ EbFH,
                                                const float* __restrict__ en,
                                                unsigned long long* __restrict__ packed,
                                                int* __restrict__ flagCnt,
                                                int* __restrict__ flagList1) {
    __shared__ unsigned short Bs[2][8192];   // 2 x 16KB fragment-ordered tile

    const int tid = threadIdx.x;
    const int w   = tid >> 6;      // wave 0..3
    const int l   = tid & 63;
    const int l4  = l >> 4;        // quad 0..3
    const int l15 = l & 15;
    const int rowBase = blockIdx.x * 128;
    const int waveRow = rowBase + w * 32;

    shortx8 A[2][8];
#pragma unroll
    for (int mt = 0; mt < 2; mt++) {
        const float* xp = X + (size_t)(waveRow + mt * 16 + l15) * DIM + l4 * 8;
#pragma unroll
        for (int kt = 0; kt < 8; kt++) {
            float4 p = *(const float4*)(xp + kt * 32);
            float4 q = *(const float4*)(xp + kt * 32 + 4);
            shortx8 v;
            v[0] = (short)f2bf(p.x); v[1] = (short)f2bf(p.y);
            v[2] = (short)f2bf(p.z); v[3] = (short)f2bf(p.w);
            v[4] = (short)f2bf(q.x); v[5] = (short)f2bf(q.y);
            v[6] = (short)f2bf(q.z); v[7] = (short)f2bf(q.w);
            A[mt][kt] = v;
        }
    }

    uint4 s0, s1, s2, s3;
    {   // prologue: stage tile 0 into buf 0 (linear: thread tid -> 64B)
        const uint4* src = (const uint4*)(EbFH + (size_t)tid * 32);
        s0 = src[0]; s1 = src[1]; s2 = src[2]; s3 = src[3];
        uint4* dst = (uint4*)&Bs[0][tid * 32];
        dst[0] = s0; dst[1] = s1; dst[2] = s2; dst[3] = s3;
    }

    float bs1[8], bs2[8];
    unsigned bc[8];
#pragma unroll
    for (int i = 0; i < 8; i++) { bs1[i] = 3.0e38f; bs2[i] = 3.0e38f; bc[i] = 0; }

    for (int ct = 0; ct < 32; ct++) {
        const int cur = ct & 1, nxt = cur ^ 1;
        __syncthreads();
        bool doNext = (ct + 1 < 32);
        if (doNext) {   // issue next-tile loads BEFORE compute (latency hides)
            const uint4* src = (const uint4*)(EbFH + (size_t)(ct + 1) * 8192 + tid * 32);
            s0 = src[0]; s1 = src[1]; s2 = src[2]; s3 = src[3];
        }
        float en0 = en[ct * 32 + l15];
        float en1 = en[ct * 32 + 16 + l15];

        floatx4 acc[2][2];
#pragma unroll
        for (int mt = 0; mt < 2; mt++)
#pragma unroll
            for (int nt = 0; nt < 2; nt++)
                acc[mt][nt] = (floatx4){0.f, 0.f, 0.f, 0.f};

#pragma unroll
        for (int kt = 0; kt < 8; kt++) {
            shortx8 b0 = *(const shortx8*)&Bs[cur][(kt * 2 + 0) * 512 + l * 8];
            shortx8 b1 = *(const shortx8*)&Bs[cur][(kt * 2 + 1) * 512 + l * 8];
            acc[0][0] = __builtin_amdgcn_mfma_f32_16x16x32_bf16(A[0][kt], b0, acc[0][0], 0, 0, 0);
            acc[0][1] = __builtin_amdgcn_mfma_f32_16x16x32_bf16(A[0][kt], b1, acc[0][1], 0, 0, 0);
            acc[1][0] = __builtin_amdgcn_mfma_f32_16x16x32_bf16(A[1][kt], b0, acc[1][0], 0, 0, 0);
            acc[1][1] = __builtin_amdgcn_mfma_f32_16x16x32_bf16(A[1][kt], b1, acc[1][1], 0, 0, 0);
        }

        {   // inline float top-2 update
            unsigned cb = (unsigned)(ct * 32 + l15);
#pragma unroll
            for (int mt = 0; mt < 2; mt++)
#pragma unroll
                for (int r = 0; r < 4; r++) {
                    float s0f = fmaf(-2.0f, acc[mt][0][r], en0);
                    float s1f = fmaf(-2.0f, acc[mt][1][r], en1);
                    float lo = fminf(s0f, s1f);
                    float hi = fmaxf(s0f, s1f);
                    unsigned cLo = (s1f < s0f) ? (cb + 16u) : cb;
                    int sl = mt * 4 + r;
                    float disp = fmaxf(bs1[sl], lo);
                    bs2[sl] = fminf(fminf(bs2[sl], hi), disp);
                    bc[sl]  = (lo < bs1[sl]) ? cLo : bc[sl];
                    bs1[sl] = fminf(bs1[sl], lo);
                }
        }

        if (doNext) {   // land the staged regs into the other buffer
            uint4* dst = (uint4*)&Bs[nxt][tid * 32];
            dst[0] = s0; dst[1] = s1; dst[2] = s2; dst[3] = s3;
        }
    }

    // ---- butterfly top-2 merge across l15; lane l15==0 writes results.
    // Cross-lane tie order differs from first-index, but ties => gap 0 <
    // MARGIN1 => flagged => pass2/pass3 re-solve exactly.
#pragma unroll
    for (int sl = 0; sl < 8; sl++) {
        float b1 = bs1[sl], b2 = bs2[sl];
        unsigned c = bc[sl];
#pragma unroll
        for (int m = 1; m < 16; m <<= 1) {
            float ob1 = __shfl_xor(b1, m, 64);
            float ob2 = __shfl_xor(b2, m, 64);
            unsigned oc = (unsigned)__shfl_xor((int)c, m, 64);
            float nb2 = fminf(fmaxf(b1, ob1), fminf(b2, ob2));
            bool take = ob1 < b1;
            b1 = take ? ob1 : b1;
            c  = take ? oc : c;
            b2 = nb2;
        }
        if (l15 == 0) {
            int mt = sl >> 2, r = sl & 3;
            int row = waveRow + mt * 16 + l4 * 4 + r;
            packed[row] = ((unsigned long long)fmap(b1) << 32) | c;
            if (b2 - b1 < MARGIN1) {
                int pos = atomicAdd(&flagCnt[0], 1);
                if (pos < FCAP1) flagList1[pos] = row;
            }
        }
    }
}

// ---------------------------------------------------------------------------
// Kernel 3 (pass2): 3-product bf16-split MFMA (xh*eh + xh*el + xl*eh) on
// pass1-flagged rows only. 32 rows/block, code dim split across the 4
// waves, no LDS staging / no main-loop barriers. B fragments read from
// fragment-ordered EbFH/EbFL (coalesced, L2-resident).
// Cross-wave top-2 merged through LDS epilogue; code sets disjoint across
// waves so the packed-u64 merge is exact.
// ---------------------------------------------------------------------------
__global__ void __launch_bounds__(256) vq_pass2(const float* __restrict__ X,
                                                const unsigned short* __restrict__ EbFH,
                                                const unsigned short* __restrict__ EbFL,
                                                const float* __restrict__ en,
                                                unsigned long long* __restrict__ packed,
                                                int* __restrict__ flagCnt,
                                                const int* __restrict__ flagList1,
                                                int* __restrict__ flagList2) {
    __shared__ unsigned long long V[4][32][16];   // 16 KB
    __shared__ unsigned W[4][32][16];             //  8 KB

    int cnt = flagCnt[0];
    if (cnt > FCAP1) cnt = FCAP1;
    const int base = blockIdx.x * 32;
    if (base >= cnt) return;

    const int tid = threadIdx.x;
    const int w = tid >> 6, l = tid & 63;
    const int l4 = l >> 4, l15 = l & 15;

    // ---- A preload (hi+lo) via row indirection; same 32 rows for all waves
    shortx8 Ah[2][8], Al[2][8];
#pragma unroll
    for (int mt = 0; mt < 2; mt++) {
        int j = base + mt * 16 + l15;
        int row = flagList1[j < cnt ? j : cnt - 1];
        const float* xp = X + (size_t)row * DIM + l4 * 8;
#pragma unroll
        for (int kt = 0; kt < 8; kt++) {
            shortx8 vh, vl;
#pragma unroll
            for (int c4 = 0; c4 < 2; c4++) {
                float4 p = *(const float4*)(xp + kt * 32 + c4 * 4);
                float f[4] = {p.x, p.y, p.z, p.w};
#pragma unroll
                for (int q = 0; q < 4; q++) {
                    unsigned short h = f2bf(f[q]);
                    vh[c4 * 4 + q] = (short)h;
                    vl[c4 * 4 + q] = (short)f2bf(f[q] - bf2f(h));
                }
            }
            Ah[mt][kt] = vh; Al[mt][kt] = vl;
        }
    }

    unsigned long long best[8];
    unsigned bsec[8];
#pragma unroll
    for (int i = 0; i < 8; i++) { best[i] = ~0ull; bsec[i] = 0xFFFFFFFFu; }

    // wave w covers codes [w*256, (w+1)*256): tiles ct = w*8 .. w*8+7
    for (int t = 0; t < 8; t++) {
        const int ct = w * 8 + t;
        const unsigned short* fbh = EbFH + (size_t)ct * 8192 + l * 8;
        const unsigned short* fbl = EbFL + (size_t)ct * 8192 + l * 8;
        float en0 = en[ct * 32 + l15];
        float en1 = en[ct * 32 + 16 + l15];

        floatx4 acc[2][2];
#pragma unroll
        for (int mt = 0; mt < 2; mt++)
#pragma unroll
            for (int nt = 0; nt < 2; nt++)
                acc[mt][nt] = (floatx4){0.f, 0.f, 0.f, 0.f};

#pragma unroll
        for (int kt = 0; kt < 8; kt++) {
            shortx8 bh0 = *(const shortx8*)(fbh + (kt * 2 + 0) * 512);
            shortx8 bh1 = *(const shortx8*)(fbh + (kt * 2 + 1) * 512);
            shortx8 bl0 = *(const shortx8*)(fbl + (kt * 2 + 0) * 512);
            shortx8 bl1 = *(const shortx8*)(fbl + (kt * 2 + 1) * 512);
#pragma unroll
            for (int mt = 0; mt < 2; mt++) {
                acc[mt][0] = __builtin_amdgcn_mfma_f32_16x16x32_bf16(Ah[mt][kt], bh0, acc[mt][0], 0, 0, 0);
                acc[mt][0] = __builtin_amdgcn_mfma_f32_16x16x32_bf16(Ah[mt][kt], bl0, acc[mt][0], 0, 0, 0);
                acc[mt][0] = __builtin_amdgcn_mfma_f32_16x16x32_bf16(Al[mt][kt], bh0, acc[mt][0], 0, 0, 0);
                acc[mt][1] = __builtin_amdgcn_mfma_f32_16x16x32_bf16(Ah[mt][kt], bh1, acc[mt][1], 0, 0, 0);
                acc[mt][1] = __builtin_amdgcn_mfma_f32_16x16x32_bf16(Ah[mt][kt], bl1, acc[mt][1], 0, 0, 0);
                acc[mt][1] = __builtin_amdgcn_mfma_f32_16x16x32_bf16(Al[mt][kt], bh1, acc[mt][1], 0, 0, 0);
            }
        }

#pragma unroll
        for (int mt = 0; mt < 2; mt++)
#pragma unroll
            for (int nt = 0; nt < 2; nt++) {
                float enc = nt ? en1 : en0;
                unsigned code = (unsigned)(ct * 32 + nt * 16 + l15);
#pragma unroll
                for (int r = 0; r < 4; r++) {
                    float s = fmaf(-2.0f, acc[mt][nt][r], enc);
                    unsigned m = fmap(s);
                    unsigned long long p = ((unsigned long long)m << 32) | code;
                    int sl = mt * 4 + r;
                    if (p < best[sl]) {
                        bsec[sl] = UMIN(bsec[sl], (unsigned)(best[sl] >> 32));
                        best[sl] = p;
                    } else {
                        bsec[sl] = UMIN(bsec[sl], m);
                    }
                }
            }
    }

    // ---- cross-wave top-2 merge (code sets disjoint across waves)
#pragma unroll
    for (int sl = 0; sl < 8; sl++) {
        int mt = sl >> 2, r = sl & 3;
        int rl = mt * 16 + l4 * 4 + r;   // row-in-block 0..31
        V[w][rl][l15] = best[sl];
        W[w][rl][l15] = bsec[sl];
    }
    __syncthreads();
    if (tid < 32 && base + tid < cnt) {
        unsigned long long b1 = ~0ull;
        unsigned b2 = 0xFFFFFFFFu;
#pragma unroll
        for (int ww = 0; ww < 4; ww++) {
#pragma unroll
            for (int i = 0; i < 16; i++) {
                unsigned long long v = V[ww][tid][i];
                unsigned wv = W[ww][tid][i];
                if (v < b1) {
                    b2 = UMIN(b2, (unsigned)(b1 >> 32));
                    b1 = v;
                    b2 = UMIN(b2, wv);
                } else {
                    b2 = UMIN(b2, (unsigned)(v >> 32));
                }
            }
        }
        int row = flagList1[base + tid];
        packed[row] = b1;
        float s1 = funmap((unsigned)(b1 >> 32));
        float s2 = funmap(b2);
        if (s2 - s1 < MARGIN2) {
            int pos = atomicAdd(&flagCnt[1], 1);
            if (pos < FCAP2) flagList2[pos] = row;
        }
    }
}

// ---------------------------------------------------------------------------
// Kernel 4 (pass3): exact fp32 re-solve for pass2-flagged rows (~O(10)).
// xn recomputed in-kernel with the bit-identical partial-sum + xor-butterfly
// + lane-0 broadcast. Threads 0..63 run the IDENTICAL sequential-d fmaf
// chain (same summation order -> same winners), same np-rounded score,
// packed-u64 first-index ties.
// ---------------------------------------------------------------------------
__global__ void __launch_bounds__(256) vq_pass3(const float* __restrict__ X,
                                                const float* __restrict__ E,
                                                const float* __restrict__ en,
                                                unsigned long long* __restrict__ packed,
                                                const int* __restrict__ flagCnt2,
                                                const int* __restrict__ flagList2) {
    __shared__ float Et[64][257];   // 64 codes x 256 dims, +1 pad
    __shared__ float xs[256];
    __shared__ unsigned long long red[64];
    int cnt = *flagCnt2;
    if (cnt > FCAP2) cnt = FCAP2;
    const int tid = threadIdx.x;

    for (int it = blockIdx.x; it < cnt; it += gridDim.x) {
        int row = flagList2[it];
        __syncthreads();   // protect xs/red reuse across it-iterations
        float xnr = 0.0f;
        if (tid < 64) {
            float4 xv = *(const float4*)&X[(size_t)row * DIM + tid * 4];
            *(float4*)&xs[tid * 4] = xv;
            float s = (xv.x * xv.x + xv.y * xv.y) + (xv.z * xv.z + xv.w * xv.w);
#pragma unroll
            for (int off = 1; off < 64; off <<= 1)
                s += __shfl_xor(s, off, 64);
            xnr = __shfl(s, 0, 64);   // lane-0 value == old xn[row] bit-exact
        }
        unsigned long long bl = ~0ull;
        for (int t = 0; t < KC / 64; t++) {
            __syncthreads();
            {   // flat-coalesced tile load: 64 codes x 256 f32 = 4096 float4
                int f4 = tid;               // + 256*q
#pragma unroll
                for (int q = 0; q < 16; q++, f4 += 256) {
                    int code = f4 >> 6;     // 64 float4 per row
                    int off4 = f4 & 63;
                    *(float4*)&Et[code][off4 * 4] =
                        *(const float4*)(E + ((size_t)(t * 64 + code) * DIM) + off4 * 4);
                }
            }
            __syncthreads();
            if (tid < 64) {
                int c = t * 64 + tid;
                const float* er = Et[tid];
                float dot = 0.0f;
#pragma unroll
                for (int d = 0; d < 256; d += 4) {
                    dot = fmaf(xs[d + 0], er[d + 0], dot);
                    dot = fmaf(xs[d + 1], er[d + 1], dot);
                    dot = fmaf(xs[d + 2], er[d + 2], dot);
                    dot = fmaf(xs[d + 3], er[d + 3], dot);
                }
                float s = fmaf(-2.0f, dot, xnr + en[c]);   // matches np rounding
                unsigned long long p =
                    ((unsigned long long)__float_as_uint(s) << 32) | (unsigned)c;
                if (p < bl) bl = p;
            }
        }
        if (tid < 64) red[tid] = bl;
        __syncthreads();
        if (tid == 0) {
            unsigned long long m = red[0];
#pragma unroll
            for (int i = 1; i < 64; i++)
                if (red[i] < m) m = red[i];
            packed[row] = m;
        }
    }
}

// ---------------------------------------------------------------------------
// Kernel 5: gather quantized rows + fused squared-diff partial sums.
// R13: reverted to the plain R7 form. R8's folded finalize (threadfence +
// completion counter) cost ~125us: device-scope fence per block x 4096
// blocks -> L2 writeback storms + same-line atomic serialization.
// ---------------------------------------------------------------------------
__global__ void __launch_bounds__(256) vq_gather(const float* __restrict__ X,
                                                 const float* __restrict__ E,
                                                 const unsigned long long* __restrict__ packed,
                                                 float* __restrict__ out,
                                                 float* __restrict__ accum) {
    const int tid = threadIdx.x;
    const int wave = tid >> 6;
    const int lane = tid & 63;
    const size_t rowBase = (size_t)blockIdx.x * 16;
    float part = 0.0f;
#pragma unroll
    for (int rr = 0; rr < 4; rr++) {
        size_t row = rowBase + wave + rr * 4;
        int code = (int)(unsigned int)(packed[row] & 0xffffffffull);
        float4 q = ((const float4*)(E + (size_t)code * DIM))[lane];
        float4 xv = ((const float4*)(X + row * DIM))[lane];
        ((float4*)(out + row * DIM))[lane] = q;
        float dx = q.x - xv.x, dy = q.y - xv.y, dz = q.z - xv.z, dw = q.w - xv.w;
        part = fmaf(dx, dx, part);
        part = fmaf(dy, dy, part);
        part = fmaf(dz, dz, part);
        part = fmaf(dw, dw, part);
    }
#pragma unroll
    for (int off = 1; off < 64; off <<= 1)
        part += __shfl_xor(part, off, 64);
    __shared__ float red[4];
    if ((tid & 63) == 0) red[tid >> 6] = part;
    __syncthreads();
    if (tid == 0) {
        float s = (red[0] + red[1]) + (red[2] + red[3]);
        atomicAdd(accum, s);
    }
}

// ---------------------------------------------------------------------------
// Kernel 6: finalize scalar loss. mean = sum / 2^24 (exact), loss = 2*mean.
// ---------------------------------------------------------------------------
__global__ void vq_finalize(const float* __restrict__ accum,
                            float* __restrict__ loss) {
    float m = *accum * (1.0f / 16777216.0f);
    *loss = m + m;
}

extern "C" void kernel_launch(void* const* d_in, const int* in_sizes, int n_in,
                              void* d_out, int out_size, void* d_ws, size_t ws_size,
                              hipStream_t stream) {
    const float* X = (const float*)d_in[0];   // [65536, 256]
    const float* E = (const float*)d_in[1];   // [1024, 256]
    float* out = (float*)d_out;               // quantized [65536*256] + loss [1]

    char* ws = (char*)d_ws;
    float* en = (float*)ws;                                           //    4096 B
    unsigned short* EbFH = (unsigned short*)(ws + 4096);              //  524288 B
    unsigned short* EbFL = (unsigned short*)(ws + 528384);            //  524288 B
    unsigned long long* packed = (unsigned long long*)(ws + 1052672); //  524288 B
    int* flagList1 = (int*)(ws + 1576960);                            //   65536 B
    int* flagList2 = (int*)(ws + 1642496);                            //   16384 B
    float* accum = (float*)(ws + 1658880);
    int* flagCnt = (int*)(ws + 1658884);                              // [cnt1, cnt2]

    vq_norms   <<<KC / 4, 256, 0, stream>>>(E, en, EbFH, EbFL, accum, flagCnt);
    vq_pass1   <<<NROWS / 128, 256, 0, stream>>>(X, EbFH, en, packed, flagCnt, flagList1);
    vq_pass2   <<<FCAP1 / 32, 256, 0, stream>>>(X, EbFH, EbFL, en, packed, flagCnt, flagList1, flagList2);
    vq_pass3   <<<64, 256, 0, stream>>>(X, E, en, packed, flagCnt + 1, flagList2);
    vq_gather  <<<NROWS / 16, 256, 0, stream>>>(X, E, packed, out, accum);
    vq_finalize<<<1, 1, 0, stream>>>(accum, out + (size_t)NROWS * DIM);
}

// Round 10
// 311.561 us; speedup vs baseline: 1.3499x; 1.0111x over previous
//
#include <hip/hip_runtime.h>
#include <math.h>

#define NROWS 65536
#define DIM 256
#define KC 1024
#define FCAP1 16384
#define FCAP2 4096
#define MARGIN1 0.024f
#define MARGIN2 5.0e-5f

typedef float  floatx4 __attribute__((ext_vector_type(4)));
typedef short  shortx8 __attribute__((ext_vector_type(8)));

__device__ __forceinline__ unsigned short f2bf(float f) {
    unsigned u = __float_as_uint(f);
    return (unsigned short)((u + 0x7fffu + ((u >> 16) & 1u)) >> 16);
}
__device__ __forceinline__ float bf2f(unsigned short h) {
    return __uint_as_float(((unsigned)h) << 16);
}
// monotone float->u32 mapping (works for negatives)
__device__ __forceinline__ unsigned fmap(float s) {
    unsigned u = __float_as_uint(s);
    return u ^ (unsigned)(((int)u >> 31) | 0x80000000);
}
__device__ __forceinline__ float funmap(unsigned m) {
    unsigned u = (m & 0x80000000u) ? (m ^ 0x80000000u) : ~m;
    return __uint_as_float(u);
}
#define UMIN(a, b) ((a) < (b) ? (a) : (b))

// Fragment-ordered E layout: for MFMA tile ct (32 codes), k-slice kt, half h
// (codes ct*32+h*16+0..15), the 64-lane B-fragment is contiguous:
//   half_idx(ct,kt,h, lane, el) = ct*8192 + (kt*2+h)*512 + lane*8 + el
// lane = l4*16+l15 holds code ct*32+h*16+l15, dims kt*32+l4*8+el.
// Tile ct = 8192 halfs = 16 KB contiguous -> linear LDS staging, and lane l
// reads byte l*16 of each 1KB fragment (conflict-free ds_read_b128).

// ---------------------------------------------------------------------------
// Kernel 1: E-only preprocessing. E row norms (en); E -> hi/lo bf16 split
// written in FRAGMENT ORDER (EbFH/EbFL); zero accum + counters.
// ---------------------------------------------------------------------------
__global__ void __launch_bounds__(256) vq_norms(const float* __restrict__ e,
                                                float* __restrict__ en,
                                                unsigned short* __restrict__ EbFH,
                                                unsigned short* __restrict__ EbFL,
                                                float* __restrict__ accum,
                                                int* __restrict__ flagCnt) {
    if (blockIdx.x == 0 && threadIdx.x == 0) {
        *accum = 0.0f; flagCnt[0] = 0; flagCnt[1] = 0;
    }
    const int wave = threadIdx.x >> 6;
    const int lane = threadIdx.x & 63;
    const int er = blockIdx.x * 4 + wave;   // grid = KC/4 exactly
    float4 v = ((const float4*)(e + (size_t)er * DIM))[lane];
    ushort4 oh, ol;
    oh.x = f2bf(v.x); ol.x = f2bf(v.x - bf2f(oh.x));
    oh.y = f2bf(v.y); ol.y = f2bf(v.y - bf2f(oh.y));
    oh.z = f2bf(v.z); ol.z = f2bf(v.z - bf2f(oh.z));
    oh.w = f2bf(v.w); ol.w = f2bf(v.w - bf2f(oh.w));
    {   // fragment-order scatter: this lane holds dims lane*4 .. lane*4+3
        const int ct  = er >> 5;
        const int l15 = er & 15;
        const int hf  = (er >> 4) & 1;
        const int kt  = lane >> 3;          // (lane*4)>>5
        const int l4  = (lane >> 1) & 3;    // ((lane*4)>>3)&3
        const int el  = (lane & 1) * 4;     // (lane*4)&7
        const size_t idx = (size_t)ct * 8192 + (kt * 2 + hf) * 512
                         + (l4 * 16 + l15) * 8 + el;
        *(ushort4*)(EbFH + idx) = oh;
        *(ushort4*)(EbFL + idx) = ol;
    }
    float s = (v.x * v.x + v.y * v.y) + (v.z * v.z + v.w * v.w);
#pragma unroll
    for (int off = 1; off < 64; off <<= 1)
        s += __shfl_xor(s, off, 64);
    if (lane == 0) en[er] = s;
}

// ---------------------------------------------------------------------------
// Kernel 2 (pass1): bf16 MFMA distance-GEMM + top-2 argmin, full codebook.
// R14 = R12 with the staging access pattern fixed:
//  - R12's thread-owns-64-contiguous-bytes staging made each ds_write_b128
//    phase hit banks {0-3,16-19} alternately -> 4-way write conflict
//    (SQ_LDS_BANK_CONFLICT 6.29M, the R9 counter read). Now thread tid
//    copies 4 stride-interleaved 16B chunks at (i*256+tid)*16: every
//    ds_write phase has lane l at byte l*16 (same as the read pattern,
//    conflict-free) and global loads are lane-consecutive (perfect
//    coalescing at 16B/lane).
//  - shape unchanged: 512 blocks x 4 waves = 2 independent blocks/CU
//    (cross-block overlap at the per-tile barrier).
//  - fragment-ordered tile, float top-2 inline update, direct flag writes.
// Scores bit-identical to R1/R6/R7 (same bf16 values, same MFMA order).
// ---------------------------------------------------------------------------
__global__ void __launch_bounds__(256) vq_pass1(const float* __restrict__ X,
                                                const unsigned short* __restrict__ EbFH,
                                                const float* __restrict__ en,
                                                unsigned long long* __restrict__ packed,
                                                int* __restrict__ flagCnt,
                                                int* __restrict__ flagList1) {
    __shared__ unsigned short Bs[2][8192];   // 2 x 16KB fragment-ordered tile

    const int tid = threadIdx.x;
    const int w   = tid >> 6;      // wave 0..3
    const int l   = tid & 63;
    const int l4  = l >> 4;        // quad 0..3
    const int l15 = l & 15;
    const int rowBase = blockIdx.x * 128;
    const int waveRow = rowBase + w * 32;

    shortx8 A[2][8];
#pragma unroll
    for (int mt = 0; mt < 2; mt++) {
        const float* xp = X + (size_t)(waveRow + mt * 16 + l15) * DIM + l4 * 8;
#pragma unroll
        for (int kt = 0; kt < 8; kt++) {
            float4 p = *(const float4*)(xp + kt * 32);
            float4 q = *(const float4*)(xp + kt * 32 + 4);
            shortx8 v;
            v[0] = (short)f2bf(p.x); v[1] = (short)f2bf(p.y);
            v[2] = (short)f2bf(p.z); v[3] = (short)f2bf(p.w);
            v[4] = (short)f2bf(q.x); v[5] = (short)f2bf(q.y);
            v[6] = (short)f2bf(q.z); v[7] = (short)f2bf(q.w);
            A[mt][kt] = v;
        }
    }

    uint4 s0, s1, s2, s3;
    {   // prologue: stage tile 0 into buf 0 (interleaved: chunk i*256+tid)
        const uint4* src = (const uint4*)EbFH;
        s0 = src[tid]; s1 = src[256 + tid]; s2 = src[512 + tid]; s3 = src[768 + tid];
        uint4* dst = (uint4*)&Bs[0][0];
        dst[tid] = s0; dst[256 + tid] = s1; dst[512 + tid] = s2; dst[768 + tid] = s3;
    }

    float bs1[8], bs2[8];
    unsigned bc[8];
#pragma unroll
    for (int i = 0; i < 8; i++) { bs1[i] = 3.0e38f; bs2[i] = 3.0e38f; bc[i] = 0; }

    for (int ct = 0; ct < 32; ct++) {
        const int cur = ct & 1, nxt = cur ^ 1;
        __syncthreads();
        bool doNext = (ct + 1 < 32);
        if (doNext) {   // issue next-tile loads BEFORE compute (latency hides)
            const uint4* src = (const uint4*)(EbFH + (size_t)(ct + 1) * 8192);
            s0 = src[tid]; s1 = src[256 + tid]; s2 = src[512 + tid]; s3 = src[768 + tid];
        }
        float en0 = en[ct * 32 + l15];
        float en1 = en[ct * 32 + 16 + l15];

        floatx4 acc[2][2];
#pragma unroll
        for (int mt = 0; mt < 2; mt++)
#pragma unroll
            for (int nt = 0; nt < 2; nt++)
                acc[mt][nt] = (floatx4){0.f, 0.f, 0.f, 0.f};

#pragma unroll
        for (int kt = 0; kt < 8; kt++) {
            shortx8 b0 = *(const shortx8*)&Bs[cur][(kt * 2 + 0) * 512 + l * 8];
            shortx8 b1 = *(const shortx8*)&Bs[cur][(kt * 2 + 1) * 512 + l * 8];
            acc[0][0] = __builtin_amdgcn_mfma_f32_16x16x32_bf16(A[0][kt], b0, acc[0][0], 0, 0, 0);
            acc[0][1] = __builtin_amdgcn_mfma_f32_16x16x32_bf16(A[0][kt], b1, acc[0][1], 0, 0, 0);
            acc[1][0] = __builtin_amdgcn_mfma_f32_16x16x32_bf16(A[1][kt], b0, acc[1][0], 0, 0, 0);
            acc[1][1] = __builtin_amdgcn_mfma_f32_16x16x32_bf16(A[1][kt], b1, acc[1][1], 0, 0, 0);
        }

        {   // inline float top-2 update
            unsigned cb = (unsigned)(ct * 32 + l15);
#pragma unroll
            for (int mt = 0; mt < 2; mt++)
#pragma unroll
                for (int r = 0; r < 4; r++) {
                    float s0f = fmaf(-2.0f, acc[mt][0][r], en0);
                    float s1f = fmaf(-2.0f, acc[mt][1][r], en1);
                    float lo = fminf(s0f, s1f);
                    float hi = fmaxf(s0f, s1f);
                    unsigned cLo = (s1f < s0f) ? (cb + 16u) : cb;
                    int sl = mt * 4 + r;
                    float disp = fmaxf(bs1[sl], lo);
                    bs2[sl] = fminf(fminf(bs2[sl], hi), disp);
                    bc[sl]  = (lo < bs1[sl]) ? cLo : bc[sl];
                    bs1[sl] = fminf(bs1[sl], lo);
                }
        }

        if (doNext) {   // land the staged regs into the other buffer
            uint4* dst = (uint4*)&Bs[nxt][0];
            dst[tid] = s0; dst[256 + tid] = s1; dst[512 + tid] = s2; dst[768 + tid] = s3;
        }
    }

    // ---- butterfly top-2 merge across l15; lane l15==0 writes results.
    // Cross-lane tie order differs from first-index, but ties => gap 0 <
    // MARGIN1 => flagged => pass2/pass3 re-solve exactly.
#pragma unroll
    for (int sl = 0; sl < 8; sl++) {
        float b1 = bs1[sl], b2 = bs2[sl];
        unsigned c = bc[sl];
#pragma unroll
        for (int m = 1; m < 16; m <<= 1) {
            float ob1 = __shfl_xor(b1, m, 64);
            float ob2 = __shfl_xor(b2, m, 64);
            unsigned oc = (unsigned)__shfl_xor((int)c, m, 64);
            float nb2 = fminf(fmaxf(b1, ob1), fminf(b2, ob2));
            bool take = ob1 < b1;
            b1 = take ? ob1 : b1;
            c  = take ? oc : c;
            b2 = nb2;
        }
        if (l15 == 0) {
            int mt = sl >> 2, r = sl & 3;
            int row = waveRow + mt * 16 + l4 * 4 + r;
            packed[row] = ((unsigned long long)fmap(b1) << 32) | c;
            if (b2 - b1 < MARGIN1) {
                int pos = atomicAdd(&flagCnt[0], 1);
                if (pos < FCAP1) flagList1[pos] = row;
            }
        }
    }
}

// ---------------------------------------------------------------------------
// Kernel 3 (pass2): 3-product bf16-split MFMA (xh*eh + xh*el + xl*eh) on
// pass1-flagged rows only. 32 rows/block, code dim split across the 4
// waves, no LDS staging / no main-loop barriers. B fragments read from
// fragment-ordered EbFH/EbFL (coalesced, L2-resident).
// Cross-wave top-2 merged through LDS epilogue; code sets disjoint across
// waves so the packed-u64 merge is exact.
// ---------------------------------------------------------------------------
__global__ void __launch_bounds__(256) vq_pass2(const float* __restrict__ X,
                                                const unsigned short* __restrict__ EbFH,
                                                const unsigned short* __restrict__ EbFL,
                                                const float* __restrict__ en,
                                                unsigned long long* __restrict__ packed,
                                                int* __restrict__ flagCnt,
                                                const int* __restrict__ flagList1,
                                                int* __restrict__ flagList2) {
    __shared__ unsigned long long V[4][32][16];   // 16 KB
    __shared__ unsigned W[4][32][16];             //  8 KB

    int cnt = flagCnt[0];
    if (cnt > FCAP1) cnt = FCAP1;
    const int base = blockIdx.x * 32;
    if (base >= cnt) return;

    const int tid = threadIdx.x;
    const int w = tid >> 6, l = tid & 63;
    const int l4 = l >> 4, l15 = l & 15;

    // ---- A preload (hi+lo) via row indirection; same 32 rows for all waves
    shortx8 Ah[2][8], Al[2][8];
#pragma unroll
    for (int mt = 0; mt < 2; mt++) {
        int j = base + mt * 16 + l15;
        int row = flagList1[j < cnt ? j : cnt - 1];
        const float* xp = X + (size_t)row * DIM + l4 * 8;
#pragma unroll
        for (int kt = 0; kt < 8; kt++) {
            shortx8 vh, vl;
#pragma unroll
            for (int c4 = 0; c4 < 2; c4++) {
                float4 p = *(const float4*)(xp + kt * 32 + c4 * 4);
                float f[4] = {p.x, p.y, p.z, p.w};
#pragma unroll
                for (int q = 0; q < 4; q++) {
                    unsigned short h = f2bf(f[q]);
                    vh[c4 * 4 + q] = (short)h;
                    vl[c4 * 4 + q] = (short)f2bf(f[q] - bf2f(h));
                }
            }
            Ah[mt][kt] = vh; Al[mt][kt] = vl;
        }
    }

    unsigned long long best[8];
    unsigned bsec[8];
#pragma unroll
    for (int i = 0; i < 8; i++) { best[i] = ~0ull; bsec[i] = 0xFFFFFFFFu; }

    // wave w covers codes [w*256, (w+1)*256): tiles ct = w*8 .. w*8+7
    for (int t = 0; t < 8; t++) {
        const int ct = w * 8 + t;
        const unsigned short* fbh = EbFH + (size_t)ct * 8192 + l * 8;
        const unsigned short* fbl = EbFL + (size_t)ct * 8192 + l * 8;
        float en0 = en[ct * 32 + l15];
        float en1 = en[ct * 32 + 16 + l15];

        floatx4 acc[2][2];
#pragma unroll
        for (int mt = 0; mt < 2; mt++)
#pragma unroll
            for (int nt = 0; nt < 2; nt++)
                acc[mt][nt] = (floatx4){0.f, 0.f, 0.f, 0.f};

#pragma unroll
        for (int kt = 0; kt < 8; kt++) {
            shortx8 bh0 = *(const shortx8*)(fbh + (kt * 2 + 0) * 512);
            shortx8 bh1 = *(const shortx8*)(fbh + (kt * 2 + 1) * 512);
            shortx8 bl0 = *(const shortx8*)(fbl + (kt * 2 + 0) * 512);
            shortx8 bl1 = *(const shortx8*)(fbl + (kt * 2 + 1) * 512);
#pragma unroll
            for (int mt = 0; mt < 2; mt++) {
                acc[mt][0] = __builtin_amdgcn_mfma_f32_16x16x32_bf16(Ah[mt][kt], bh0, acc[mt][0], 0, 0, 0);
                acc[mt][0] = __builtin_amdgcn_mfma_f32_16x16x32_bf16(Ah[mt][kt], bl0, acc[mt][0], 0, 0, 0);
                acc[mt][0] = __builtin_amdgcn_mfma_f32_16x16x32_bf16(Al[mt][kt], bh0, acc[mt][0], 0, 0, 0);
                acc[mt][1] = __builtin_amdgcn_mfma_f32_16x16x32_bf16(Ah[mt][kt], bh1, acc[mt][1], 0, 0, 0);
                acc[mt][1] = __builtin_amdgcn_mfma_f32_16x16x32_bf16(Ah[mt][kt], bl1, acc[mt][1], 0, 0, 0);
                acc[mt][1] = __builtin_amdgcn_mfma_f32_16x16x32_bf16(Al[mt][kt], bh1, acc[mt][1], 0, 0, 0);
            }
        }

#pragma unroll
        for (int mt = 0; mt < 2; mt++)
#pragma unroll
            for (int nt = 0; nt < 2; nt++) {
                float enc = nt ? en1 : en0;
                unsigned code = (unsigned)(ct * 32 + nt * 16 + l15);
#pragma unroll
                for (int r = 0; r < 4; r++) {
                    float s = fmaf(-2.0f, acc[mt][nt][r], enc);
                    unsigned m = fmap(s);
                    unsigned long long p = ((unsigned long long)m << 32) | code;
                    int sl = mt * 4 + r;
                    if (p < best[sl]) {
                        bsec[sl] = UMIN(bsec[sl], (unsigned)(best[sl] >> 32));
                        best[sl] = p;
                    } else {
                        bsec[sl] = UMIN(bsec[sl], m);
                    }
                }
            }
    }

    // ---- cross-wave top-2 merge (code sets disjoint across waves)
#pragma unroll
    for (int sl = 0; sl < 8; sl++) {
        int mt = sl >> 2, r = sl & 3;
        int rl = mt * 16 + l4 * 4 + r;   // row-in-block 0..31
        V[w][rl][l15] = best[sl];
        W[w][rl][l15] = bsec[sl];
    }
    __syncthreads();
    if (tid < 32 && base + tid < cnt) {
        unsigned long long b1 = ~0ull;
        unsigned b2 = 0xFFFFFFFFu;
#pragma unroll
        for (int ww = 0; ww < 4; ww++) {
#pragma unroll
            for (int i = 0; i < 16; i++) {
                unsigned long long v = V[ww][tid][i];
                unsigned wv = W[ww][tid][i];
                if (v < b1) {
                    b2 = UMIN(b2, (unsigned)(b1 >> 32));
                    b1 = v;
                    b2 = UMIN(b2, wv);
                } else {
                    b2 = UMIN(b2, (unsigned)(v >> 32));
                }
            }
        }
        int row = flagList1[base + tid];
        packed[row] = b1;
        float s1 = funmap((unsigned)(b1 >> 32));
        float s2 = funmap(b2);
        if (s2 - s1 < MARGIN2) {
            int pos = atomicAdd(&flagCnt[1], 1);
            if (pos < FCAP2) flagList2[pos] = row;
        }
    }
}

// ---------------------------------------------------------------------------
// Kernel 4 (pass3): exact fp32 re-solve for pass2-flagged rows (~O(10)).
// xn recomputed in-kernel with the bit-identical partial-sum + xor-butterfly
// + lane-0 broadcast. Threads 0..63 run the IDENTICAL sequential-d fmaf
// chain (same summation order -> same winners), same np-rounded score,
// packed-u64 first-index ties.
// ---------------------------------------------------------------------------
__global__ void __launch_bounds__(256) vq_pass3(const float* __restrict__ X,
                                                const float* __restrict__ E,
                                                const float* __restrict__ en,
                                                unsigned long long* __restrict__ packed,
                                                const int* __restrict__ flagCnt2,
                                                const int* __restrict__ flagList2) {
    __shared__ float Et[64][257];   // 64 codes x 256 dims, +1 pad
    __shared__ float xs[256];
    __shared__ unsigned long long red[64];
    int cnt = *flagCnt2;
    if (cnt > FCAP2) cnt = FCAP2;
    const int tid = threadIdx.x;

    for (int it = blockIdx.x; it < cnt; it += gridDim.x) {
        int row = flagList2[it];
        __syncthreads();   // protect xs/red reuse across it-iterations
        float xnr = 0.0f;
        if (tid < 64) {
            float4 xv = *(const float4*)&X[(size_t)row * DIM + tid * 4];
            *(float4*)&xs[tid * 4] = xv;
            float s = (xv.x * xv.x + xv.y * xv.y) + (xv.z * xv.z + xv.w * xv.w);
#pragma unroll
            for (int off = 1; off < 64; off <<= 1)
                s += __shfl_xor(s, off, 64);
            xnr = __shfl(s, 0, 64);   // lane-0 value == old xn[row] bit-exact
        }
        unsigned long long bl = ~0ull;
        for (int t = 0; t < KC / 64; t++) {
            __syncthreads();
            {   // flat-coalesced tile load: 64 codes x 256 f32 = 4096 float4
                int f4 = tid;               // + 256*q
#pragma unroll
                for (int q = 0; q < 16; q++, f4 += 256) {
                    int code = f4 >> 6;     // 64 float4 per row
                    int off4 = f4 & 63;
                    *(float4*)&Et[code][off4 * 4] =
                        *(const float4*)(E + ((size_t)(t * 64 + code) * DIM) + off4 * 4);
                }
            }
            __syncthreads();
            if (tid < 64) {
                int c = t * 64 + tid;
                const float* er = Et[tid];
                float dot = 0.0f;
#pragma unroll
                for (int d = 0; d < 256; d += 4) {
                    dot = fmaf(xs[d + 0], er[d + 0], dot);
                    dot = fmaf(xs[d + 1], er[d + 1], dot);
                    dot = fmaf(xs[d + 2], er[d + 2], dot);
                    dot = fmaf(xs[d + 3], er[d + 3], dot);
                }
                float s = fmaf(-2.0f, dot, xnr + en[c]);   // matches np rounding
                unsigned long long p =
                    ((unsigned long long)__float_as_uint(s) << 32) | (unsigned)c;
                if (p < bl) bl = p;
            }
        }
        if (tid < 64) red[tid] = bl;
        __syncthreads();
        if (tid == 0) {
            unsigned long long m = red[0];
#pragma unroll
            for (int i = 1; i < 64; i++)
                if (red[i] < m) m = red[i];
            packed[row] = m;
        }
    }
}

// ---------------------------------------------------------------------------
// Kernel 5: gather quantized rows + fused squared-diff partial sums.
// (Plain form; R8's folded finalize cost ~125us in fence traffic.)
// ---------------------------------------------------------------------------
__global__ void __launch_bounds__(256) vq_gather(const float* __restrict__ X,
                                                 const float* __restrict__ E,
                                                 const unsigned long long* __restrict__ packed,
                                                 float* __restrict__ out,
                                                 float* __restrict__ accum) {
    const int tid = threadIdx.x;
    const int wave = tid >> 6;
    const int lane = tid & 63;
    const size_t rowBase = (size_t)blockIdx.x * 16;
    float part = 0.0f;
#pragma unroll
    for (int rr = 0; rr < 4; rr++) {
        size_t row = rowBase + wave + rr * 4;
        int code = (int)(unsigned int)(packed[row] & 0xffffffffull);
        float4 q = ((const float4*)(E + (size_t)code * DIM))[lane];
        float4 xv = ((const float4*)(X + row * DIM))[lane];
        ((float4*)(out + row * DIM))[lane] = q;
        float dx = q.x - xv.x, dy = q.y - xv.y, dz = q.z - xv.z, dw = q.w - xv.w;
        part = fmaf(dx, dx, part);
        part = fmaf(dy, dy, part);
        part = fmaf(dz, dz, part);
        part = fmaf(dw, dw, part);
    }
#pragma unroll
    for (int off = 1; off < 64; off <<= 1)
        part += __shfl_xor(part, off, 64);
    __shared__ float red[4];
    if ((tid & 63) == 0) red[tid >> 6] = part;
    __syncthreads();
    if (tid == 0) {
        float s = (red[0] + red[1]) + (red[2] + red[3]);
        atomicAdd(accum, s);
    }
}

// ---------------------------------------------------------------------------
// Kernel 6: finalize scalar loss. mean = sum / 2^24 (exact), loss = 2*mean.
// ---------------------------------------------------------------------------
__global__ void vq_finalize(const float* __restrict__ accum,
                            float* __restrict__ loss) {
    float m = *accum * (1.0f / 16777216.0f);
    *loss = m + m;
}

extern "C" void kernel_launch(void* const* d_in, const int* in_sizes, int n_in,
                              void* d_out, int out_size, void* d_ws, size_t ws_size,
                              hipStream_t stream) {
    const float* X = (const float*)d_in[0];   // [65536, 256]
    const float* E = (const float*)d_in[1];   // [1024, 256]
    float* out = (float*)d_out;               // quantized [65536*256] + loss [1]

    char* ws = (char*)d_ws;
    float* en = (float*)ws;                                           //    4096 B
    unsigned short* EbFH = (unsigned short*)(ws + 4096);              //  524288 B
    unsigned short* EbFL = (unsigned short*)(ws + 528384);            //  524288 B
    unsigned long long* packed = (unsigned long long*)(ws + 1052672); //  524288 B
    int* flagList1 = (int*)(ws + 1576960);                            //   65536 B
    int* flagList2 = (int*)(ws + 1642496);                            //   16384 B
    float* accum = (float*)(ws + 1658880);
    int* flagCnt = (int*)(ws + 1658884);                              // [cnt1, cnt2]

    vq_norms   <<<KC / 4, 256, 0, stream>>>(E, en, EbFH, EbFL, accum, flagCnt);
    vq_pass1   <<<NROWS / 128, 256, 0, stream>>>(X, EbFH, en, packed, flagCnt, flagList1);
    vq_pass2   <<<FCAP1 / 32, 256, 0, stream>>>(X, EbFH, EbFL, en, packed, flagCnt, flagList1, flagList2);
    vq_pass3   <<<64, 256, 0, stream>>>(X, E, en, packed, flagCnt + 1, flagList2);
    vq_gather  <<<NROWS / 16, 256, 0, stream>>>(X, E, packed, out, accum);
    vq_finalize<<<1, 1, 0, stream>>>(accum, out + (size_t)NROWS * DIM);
}

// Round 11
// 307.814 us; speedup vs baseline: 1.3663x; 1.0122x over previous
//
#include <hip/hip_runtime.h>
#include <math.h>

#define NROWS 65536
#define DIM 256
#define KC 1024
#define FCAP1 16384
#define FCAP2 4096
#define MARGIN1 0.024f
#define MARGIN2 5.0e-5f

typedef float  floatx4 __attribute__((ext_vector_type(4)));
typedef short  shortx8 __attribute__((ext_vector_type(8)));

typedef __attribute__((address_space(1))) const unsigned int gas_u32;
typedef __attribute__((address_space(3))) unsigned int las_u32;

__device__ __forceinline__ unsigned short f2bf(float f) {
    unsigned u = __float_as_uint(f);
    return (unsigned short)((u + 0x7fffu + ((u >> 16) & 1u)) >> 16);
}
__device__ __forceinline__ float bf2f(unsigned short h) {
    return __uint_as_float(((unsigned)h) << 16);
}
// monotone float->u32 mapping (works for negatives)
__device__ __forceinline__ unsigned fmap(float s) {
    unsigned u = __float_as_uint(s);
    return u ^ (unsigned)(((int)u >> 31) | 0x80000000);
}
__device__ __forceinline__ float funmap(unsigned m) {
    unsigned u = (m & 0x80000000u) ? (m ^ 0x80000000u) : ~m;
    return __uint_as_float(u);
}
#define UMIN(a, b) ((a) < (b) ? (a) : (b))

// Fragment-ordered E layout: for MFMA tile ct (32 codes), k-slice kt, half h
// (codes ct*32+h*16+0..15), the 64-lane B-fragment is contiguous:
//   half_idx(ct,kt,h, lane, el) = ct*8192 + (kt*2+h)*512 + lane*8 + el
// lane = l4*16+l15 holds code ct*32+h*16+l15, dims kt*32+l4*8+el.
// Tile ct = 8192 halfs = 16 KB contiguous -> linear LDS staging (the exact
// wave-uniform-base + lane*16B pattern global_load_lds requires), and lane l
// reads byte l*16 of each 1KB fragment (conflict-free ds_read_b128).

// ---------------------------------------------------------------------------
// Kernel 1: E-only preprocessing. E row norms (en); E -> hi/lo bf16 split
// written in FRAGMENT ORDER (EbFH/EbFL); zero accum + counters.
// ---------------------------------------------------------------------------
__global__ void __launch_bounds__(256) vq_norms(const float* __restrict__ e,
                                                float* __restrict__ en,
                                                unsigned short* __restrict__ EbFH,
                                                unsigned short* __restrict__ EbFL,
                                                float* __restrict__ accum,
                                                int* __restrict__ flagCnt) {
    if (blockIdx.x == 0 && threadIdx.x == 0) {
        *accum = 0.0f; flagCnt[0] = 0; flagCnt[1] = 0;
    }
    const int wave = threadIdx.x >> 6;
    const int lane = threadIdx.x & 63;
    const int er = blockIdx.x * 4 + wave;   // grid = KC/4 exactly
    float4 v = ((const float4*)(e + (size_t)er * DIM))[lane];
    ushort4 oh, ol;
    oh.x = f2bf(v.x); ol.x = f2bf(v.x - bf2f(oh.x));
    oh.y = f2bf(v.y); ol.y = f2bf(v.y - bf2f(oh.y));
    oh.z = f2bf(v.z); ol.z = f2bf(v.z - bf2f(oh.z));
    oh.w = f2bf(v.w); ol.w = f2bf(v.w - bf2f(oh.w));
    {   // fragment-order scatter: this lane holds dims lane*4 .. lane*4+3
        const int ct  = er >> 5;
        const int l15 = er & 15;
        const int hf  = (er >> 4) & 1;
        const int kt  = lane >> 3;          // (lane*4)>>5
        const int l4  = (lane >> 1) & 3;    // ((lane*4)>>3)&3
        const int el  = (lane & 1) * 4;     // (lane*4)&7
        const size_t idx = (size_t)ct * 8192 + (kt * 2 + hf) * 512
                         + (l4 * 16 + l15) * 8 + el;
        *(ushort4*)(EbFH + idx) = oh;
        *(ushort4*)(EbFL + idx) = ol;
    }
    float s = (v.x * v.x + v.y * v.y) + (v.z * v.z + v.w * v.w);
#pragma unroll
    for (int off = 1; off < 64; off <<= 1)
        s += __shfl_xor(s, off, 64);
    if (lane == 0) en[er] = s;
}

// ---------------------------------------------------------------------------
// Kernel 2 (pass1): bf16 MFMA distance-GEMM + top-2 argmin, full codebook.
// R15 = R14 with staging switched to async global_load_lds (width=16):
//  - R10's counter read: conflicts 0, coalescing perfect, yet 82-89us with
//    all pipes <22% -- the per-tile serial chain was global->VGPR (vmcnt
//    wait) -> ds_write -> barrier lgkm drain, repeated 32x in lockstep.
//  - global_load_lds moves bytes direct to LDS: no VGPR roundtrip, no
//    ds_write; the loads are issued right after the barrier and have the
//    whole tile's compute (~600+cy) to land, so the next barrier's vmcnt(0)
//    drain finds them complete. Our linear fragment staging is exactly the
//    required wave-uniform-base + lane*16B pattern (impossible with R1's
//    padded layout).
//  - shape unchanged: 512 blocks x 4 waves = 2 independent blocks/CU.
//  - fragment-ordered tile, float top-2 inline update, direct flag writes.
// Bytes moved are identical -> scores bit-identical to R1/R6/R7/R14.
// ---------------------------------------------------------------------------
__global__ void __launch_bounds__(256) vq_pass1(const float* __restrict__ X,
                                                const unsigned short* __restrict__ EbFH,
                                                const float* __restrict__ en,
                                                unsigned long long* __restrict__ packed,
                                                int* __restrict__ flagCnt,
                                                int* __restrict__ flagList1) {
    __shared__ unsigned short Bs[2][8192];   // 2 x 16KB fragment-ordered tile

    const int tid = threadIdx.x;
    const int w   = tid >> 6;      // wave 0..3
    const int l   = tid & 63;
    const int l4  = l >> 4;        // quad 0..3
    const int l15 = l & 15;
    const int rowBase = blockIdx.x * 128;
    const int waveRow = rowBase + w * 32;

    shortx8 A[2][8];
#pragma unroll
    for (int mt = 0; mt < 2; mt++) {
        const float* xp = X + (size_t)(waveRow + mt * 16 + l15) * DIM + l4 * 8;
#pragma unroll
        for (int kt = 0; kt < 8; kt++) {
            float4 p = *(const float4*)(xp + kt * 32);
            float4 q = *(const float4*)(xp + kt * 32 + 4);
            shortx8 v;
            v[0] = (short)f2bf(p.x); v[1] = (short)f2bf(p.y);
            v[2] = (short)f2bf(p.z); v[3] = (short)f2bf(p.w);
            v[4] = (short)f2bf(q.x); v[5] = (short)f2bf(q.y);
            v[6] = (short)f2bf(q.z); v[7] = (short)f2bf(q.w);
            A[mt][kt] = v;
        }
    }

    {   // prologue: async-stage tile 0 into buf 0 (16B/chunk, lane-linear)
        const unsigned short* src = EbFH;
        unsigned short* dst = &Bs[0][0];
#pragma unroll
        for (int i = 0; i < 4; i++)
            __builtin_amdgcn_global_load_lds(
                (gas_u32*)(src + (i * 256 + tid) * 8),
                (las_u32*)(dst + (i * 256 + tid) * 8), 16, 0, 0);
    }

    float bs1[8], bs2[8];
    unsigned bc[8];
#pragma unroll
    for (int i = 0; i < 8; i++) { bs1[i] = 3.0e38f; bs2[i] = 3.0e38f; bc[i] = 0; }

    for (int ct = 0; ct < 32; ct++) {
        const int cur = ct & 1, nxt = cur ^ 1;
        __syncthreads();   // drains vmcnt: tile ct's async loads complete
        bool doNext = (ct + 1 < 32);
        if (doNext) {   // async-stage next tile; whole tile-compute hides it
            const unsigned short* src = EbFH + (size_t)(ct + 1) * 8192;
            unsigned short* dst = &Bs[nxt][0];
#pragma unroll
            for (int i = 0; i < 4; i++)
                __builtin_amdgcn_global_load_lds(
                    (gas_u32*)(src + (i * 256 + tid) * 8),
                    (las_u32*)(dst + (i * 256 + tid) * 8), 16, 0, 0);
        }
        float en0 = en[ct * 32 + l15];
        float en1 = en[ct * 32 + 16 + l15];

        floatx4 acc[2][2];
#pragma unroll
        for (int mt = 0; mt < 2; mt++)
#pragma unroll
            for (int nt = 0; nt < 2; nt++)
                acc[mt][nt] = (floatx4){0.f, 0.f, 0.f, 0.f};

#pragma unroll
        for (int kt = 0; kt < 8; kt++) {
            shortx8 b0 = *(const shortx8*)&Bs[cur][(kt * 2 + 0) * 512 + l * 8];
            shortx8 b1 = *(const shortx8*)&Bs[cur][(kt * 2 + 1) * 512 + l * 8];
            acc[0][0] = __builtin_amdgcn_mfma_f32_16x16x32_bf16(A[0][kt], b0, acc[0][0], 0, 0, 0);
            acc[0][1] = __builtin_amdgcn_mfma_f32_16x16x32_bf16(A[0][kt], b1, acc[0][1], 0, 0, 0);
            acc[1][0] = __builtin_amdgcn_mfma_f32_16x16x32_bf16(A[1][kt], b0, acc[1][0], 0, 0, 0);
            acc[1][1] = __builtin_amdgcn_mfma_f32_16x16x32_bf16(A[1][kt], b1, acc[1][1], 0, 0, 0);
        }

        {   // inline float top-2 update
            unsigned cb = (unsigned)(ct * 32 + l15);
#pragma unroll
            for (int mt = 0; mt < 2; mt++)
#pragma unroll
                for (int r = 0; r < 4; r++) {
                    float s0f = fmaf(-2.0f, acc[mt][0][r], en0);
                    float s1f = fmaf(-2.0f, acc[mt][1][r], en1);
                    float lo = fminf(s0f, s1f);
                    float hi = fmaxf(s0f, s1f);
                    unsigned cLo = (s1f < s0f) ? (cb + 16u) : cb;
                    int sl = mt * 4 + r;
                    float disp = fmaxf(bs1[sl], lo);
                    bs2[sl] = fminf(fminf(bs2[sl], hi), disp);
                    bc[sl]  = (lo < bs1[sl]) ? cLo : bc[sl];
                    bs1[sl] = fminf(bs1[sl], lo);
                }
        }
    }

    // ---- butterfly top-2 merge across l15; lane l15==0 writes results.
    // Cross-lane tie order differs from first-index, but ties => gap 0 <
    // MARGIN1 => flagged => pass2/pass3 re-solve exactly.
#pragma unroll
    for (int sl = 0; sl < 8; sl++) {
        float b1 = bs1[sl], b2 = bs2[sl];
        unsigned c = bc[sl];
#pragma unroll
        for (int m = 1; m < 16; m <<= 1) {
            float ob1 = __shfl_xor(b1, m, 64);
            float ob2 = __shfl_xor(b2, m, 64);
            unsigned oc = (unsigned)__shfl_xor((int)c, m, 64);
            float nb2 = fminf(fmaxf(b1, ob1), fminf(b2, ob2));
            bool take = ob1 < b1;
            b1 = take ? ob1 : b1;
            c  = take ? oc : c;
            b2 = nb2;
        }
        if (l15 == 0) {
            int mt = sl >> 2, r = sl & 3;
            int row = waveRow + mt * 16 + l4 * 4 + r;
            packed[row] = ((unsigned long long)fmap(b1) << 32) | c;
            if (b2 - b1 < MARGIN1) {
                int pos = atomicAdd(&flagCnt[0], 1);
                if (pos < FCAP1) flagList1[pos] = row;
            }
        }
    }
}

// ---------------------------------------------------------------------------
// Kernel 3 (pass2): 3-product bf16-split MFMA (xh*eh + xh*el + xl*eh) on
// pass1-flagged rows only. 32 rows/block, code dim split across the 4
// waves, no LDS staging / no main-loop barriers. B fragments read from
// fragment-ordered EbFH/EbFL (coalesced, L2-resident).
// Cross-wave top-2 merged through LDS epilogue; code sets disjoint across
// waves so the packed-u64 merge is exact.
// ---------------------------------------------------------------------------
__global__ void __launch_bounds__(256) vq_pass2(const float* __restrict__ X,
                                                const unsigned short* __restrict__ EbFH,
                                                const unsigned short* __restrict__ EbFL,
                                                const float* __restrict__ en,
                                                unsigned long long* __restrict__ packed,
                                                int* __restrict__ flagCnt,
                                                const int* __restrict__ flagList1,
                                                int* __restrict__ flagList2) {
    __shared__ unsigned long long V[4][32][16];   // 16 KB
    __shared__ unsigned W[4][32][16];             //  8 KB

    int cnt = flagCnt[0];
    if (cnt > FCAP1) cnt = FCAP1;
    const int base = blockIdx.x * 32;
    if (base >= cnt) return;

    const int tid = threadIdx.x;
    const int w = tid >> 6, l = tid & 63;
    const int l4 = l >> 4, l15 = l & 15;

    // ---- A preload (hi+lo) via row indirection; same 32 rows for all waves
    shortx8 Ah[2][8], Al[2][8];
#pragma unroll
    for (int mt = 0; mt < 2; mt++) {
        int j = base + mt * 16 + l15;
        int row = flagList1[j < cnt ? j : cnt - 1];
        const float* xp = X + (size_t)row * DIM + l4 * 8;
#pragma unroll
        for (int kt = 0; kt < 8; kt++) {
            shortx8 vh, vl;
#pragma unroll
            for (int c4 = 0; c4 < 2; c4++) {
                float4 p = *(const float4*)(xp + kt * 32 + c4 * 4);
                float f[4] = {p.x, p.y, p.z, p.w};
#pragma unroll
                for (int q = 0; q < 4; q++) {
                    unsigned short h = f2bf(f[q]);
                    vh[c4 * 4 + q] = (short)h;
                    vl[c4 * 4 + q] = (short)f2bf(f[q] - bf2f(h));
                }
            }
            Ah[mt][kt] = vh; Al[mt][kt] = vl;
        }
    }

    unsigned long long best[8];
    unsigned bsec[8];
#pragma unroll
    for (int i = 0; i < 8; i++) { best[i] = ~0ull; bsec[i] = 0xFFFFFFFFu; }

    // wave w covers codes [w*256, (w+1)*256): tiles ct = w*8 .. w*8+7
    for (int t = 0; t < 8; t++) {
        const int ct = w * 8 + t;
        const unsigned short* fbh = EbFH + (size_t)ct * 8192 + l * 8;
        const unsigned short* fbl = EbFL + (size_t)ct * 8192 + l * 8;
        float en0 = en[ct * 32 + l15];
        float en1 = en[ct * 32 + 16 + l15];

        floatx4 acc[2][2];
#pragma unroll
        for (int mt = 0; mt < 2; mt++)
#pragma unroll
            for (int nt = 0; nt < 2; nt++)
                acc[mt][nt] = (floatx4){0.f, 0.f, 0.f, 0.f};

#pragma unroll
        for (int kt = 0; kt < 8; kt++) {
            shortx8 bh0 = *(const shortx8*)(fbh + (kt * 2 + 0) * 512);
            shortx8 bh1 = *(const shortx8*)(fbh + (kt * 2 + 1) * 512);
            shortx8 bl0 = *(const shortx8*)(fbl + (kt * 2 + 0) * 512);
            shortx8 bl1 = *(const shortx8*)(fbl + (kt * 2 + 1) * 512);
#pragma unroll
            for (int mt = 0; mt < 2; mt++) {
                acc[mt][0] = __builtin_amdgcn_mfma_f32_16x16x32_bf16(Ah[mt][kt], bh0, acc[mt][0], 0, 0, 0);
                acc[mt][0] = __builtin_amdgcn_mfma_f32_16x16x32_bf16(Ah[mt][kt], bl0, acc[mt][0], 0, 0, 0);
                acc[mt][0] = __builtin_amdgcn_mfma_f32_16x16x32_bf16(Al[mt][kt], bh0, acc[mt][0], 0, 0, 0);
                acc[mt][1] = __builtin_amdgcn_mfma_f32_16x16x32_bf16(Ah[mt][kt], bh1, acc[mt][1], 0, 0, 0);
                acc[mt][1] = __builtin_amdgcn_mfma_f32_16x16x32_bf16(Ah[mt][kt], bl1, acc[mt][1], 0, 0, 0);
                acc[mt][1] = __builtin_amdgcn_mfma_f32_16x16x32_bf16(Al[mt][kt], bh1, acc[mt][1], 0, 0, 0);
            }
        }

#pragma unroll
        for (int mt = 0; mt < 2; mt++)
#pragma unroll
            for (int nt = 0; nt < 2; nt++) {
                float enc = nt ? en1 : en0;
                unsigned code = (unsigned)(ct * 32 + nt * 16 + l15);
#pragma unroll
                for (int r = 0; r < 4; r++) {
                    float s = fmaf(-2.0f, acc[mt][nt][r], enc);
                    unsigned m = fmap(s);
                    unsigned long long p = ((unsigned long long)m << 32) | code;
                    int sl = mt * 4 + r;
                    if (p < best[sl]) {
                        bsec[sl] = UMIN(bsec[sl], (unsigned)(best[sl] >> 32));
                        best[sl] = p;
                    } else {
                        bsec[sl] = UMIN(bsec[sl], m);
                    }
                }
            }
    }

    // ---- cross-wave top-2 merge (code sets disjoint across waves)
#pragma unroll
    for (int sl = 0; sl < 8; sl++) {
        int mt = sl >> 2, r = sl & 3;
        int rl = mt * 16 + l4 * 4 + r;   // row-in-block 0..31
        V[w][rl][l15] = best[sl];
        W[w][rl][l15] = bsec[sl];
    }
    __syncthreads();
    if (tid < 32 && base + tid < cnt) {
        unsigned long long b1 = ~0ull;
        unsigned b2 = 0xFFFFFFFFu;
#pragma unroll
        for (int ww = 0; ww < 4; ww++) {
#pragma unroll
            for (int i = 0; i < 16; i++) {
                unsigned long long v = V[ww][tid][i];
                unsigned wv = W[ww][tid][i];
                if (v < b1) {
                    b2 = UMIN(b2, (unsigned)(b1 >> 32));
                    b1 = v;
                    b2 = UMIN(b2, wv);
                } else {
                    b2 = UMIN(b2, (unsigned)(v >> 32));
                }
            }
        }
        int row = flagList1[base + tid];
        packed[row] = b1;
        float s1 = funmap((unsigned)(b1 >> 32));
        float s2 = funmap(b2);
        if (s2 - s1 < MARGIN2) {
            int pos = atomicAdd(&flagCnt[1], 1);
            if (pos < FCAP2) flagList2[pos] = row;
        }
    }
}

// ---------------------------------------------------------------------------
// Kernel 4 (pass3): exact fp32 re-solve for pass2-flagged rows (~O(10)).
// xn recomputed in-kernel with the bit-identical partial-sum + xor-butterfly
// + lane-0 broadcast. Threads 0..63 run the IDENTICAL sequential-d fmaf
// chain (same summation order -> same winners), same np-rounded score,
// packed-u64 first-index ties.
// ---------------------------------------------------------------------------
__global__ void __launch_bounds__(256) vq_pass3(const float* __restrict__ X,
                                                const float* __restrict__ E,
                                                const float* __restrict__ en,
                                                unsigned long long* __restrict__ packed,
                                                const int* __restrict__ flagCnt2,
                                                const int* __restrict__ flagList2) {
    __shared__ float Et[64][257];   // 64 codes x 256 dims, +1 pad
    __shared__ float xs[256];
    __shared__ unsigned long long red[64];
    int cnt = *flagCnt2;
    if (cnt > FCAP2) cnt = FCAP2;
    const int tid = threadIdx.x;

    for (int it = blockIdx.x; it < cnt; it += gridDim.x) {
        int row = flagList2[it];
        __syncthreads();   // protect xs/red reuse across it-iterations
        float xnr = 0.0f;
        if (tid < 64) {
            float4 xv = *(const float4*)&X[(size_t)row * DIM + tid * 4];
            *(float4*)&xs[tid * 4] = xv;
            float s = (xv.x * xv.x + xv.y * xv.y) + (xv.z * xv.z + xv.w * xv.w);
#pragma unroll
            for (int off = 1; off < 64; off <<= 1)
                s += __shfl_xor(s, off, 64);
            xnr = __shfl(s, 0, 64);   // lane-0 value == old xn[row] bit-exact
        }
        unsigned long long bl = ~0ull;
        for (int t = 0; t < KC / 64; t++) {
            __syncthreads();
            {   // flat-coalesced tile load: 64 codes x 256 f32 = 4096 float4
                int f4 = tid;               // + 256*q
#pragma unroll
                for (int q = 0; q < 16; q++, f4 += 256) {
                    int code = f4 >> 6;     // 64 float4 per row
                    int off4 = f4 & 63;
                    *(float4*)&Et[code][off4 * 4] =
                        *(const float4*)(E + ((size_t)(t * 64 + code) * DIM) + off4 * 4);
                }
            }
            __syncthreads();
            if (tid < 64) {
                int c = t * 64 + tid;
                const float* er = Et[tid];
                float dot = 0.0f;
#pragma unroll
                for (int d = 0; d < 256; d += 4) {
                    dot = fmaf(xs[d + 0], er[d + 0], dot);
                    dot = fmaf(xs[d + 1], er[d + 1], dot);
                    dot = fmaf(xs[d + 2], er[d + 2], dot);
                    dot = fmaf(xs[d + 3], er[d + 3], dot);
                }
                float s = fmaf(-2.0f, dot, xnr + en[c]);   // matches np rounding
                unsigned long long p =
                    ((unsigned long long)__float_as_uint(s) << 32) | (unsigned)c;
                if (p < bl) bl = p;
            }
        }
        if (tid < 64) red[tid] = bl;
        __syncthreads();
        if (tid == 0) {
            unsigned long long m = red[0];
#pragma unroll
            for (int i = 1; i < 64; i++)
                if (red[i] < m) m = red[i];
            packed[row] = m;
        }
    }
}

// ---------------------------------------------------------------------------
// Kernel 5: gather quantized rows + fused squared-diff partial sums.
// (Plain form; R8's folded finalize cost ~125us in fence traffic.)
// ---------------------------------------------------------------------------
__global__ void __launch_bounds__(256) vq_gather(const float* __restrict__ X,
                                                 const float* __restrict__ E,
                                                 const unsigned long long* __restrict__ packed,
                                                 float* __restrict__ out,
                                                 float* __restrict__ accum) {
    const int tid = threadIdx.x;
    const int wave = tid >> 6;
    const int lane = tid & 63;
    const size_t rowBase = (size_t)blockIdx.x * 16;
    float part = 0.0f;
#pragma unroll
    for (int rr = 0; rr < 4; rr++) {
        size_t row = rowBase + wave + rr * 4;
        int code = (int)(unsigned int)(packed[row] & 0xffffffffull);
        float4 q = ((const float4*)(E + (size_t)code * DIM))[lane];
        float4 xv = ((const float4*)(X + row * DIM))[lane];
        ((float4*)(out + row * DIM))[lane] = q;
        float dx = q.x - xv.x, dy = q.y - xv.y, dz = q.z - xv.z, dw = q.w - xv.w;
        part = fmaf(dx, dx, part);
        part = fmaf(dy, dy, part);
        part = fmaf(dz, dz, part);
        part = fmaf(dw, dw, part);
    }
#pragma unroll
    for (int off = 1; off < 64; off <<= 1)
        part += __shfl_xor(part, off, 64);
    __shared__ float red[4];
    if ((tid & 63) == 0) red[tid >> 6] = part;
    __syncthreads();
    if (tid == 0) {
        float s = (red[0] + red[1]) + (red[2] + red[3]);
        atomicAdd(accum, s);
    }
}

// ---------------------------------------------------------------------------
// Kernel 6: finalize scalar loss. mean = sum / 2^24 (exact), loss = 2*mean.
// ---------------------------------------------------------------------------
__global__ void vq_finalize(const float* __restrict__ accum,
                            float* __restrict__ loss) {
    float m = *accum * (1.0f / 16777216.0f);
    *loss = m + m;
}

extern "C" void kernel_launch(void* const* d_in, const int* in_sizes, int n_in,
                              void* d_out, int out_size, void* d_ws, size_t ws_size,
                              hipStream_t stream) {
    const float* X = (const float*)d_in[0];   // [65536, 256]
    const float* E = (const float*)d_in[1];   // [1024, 256]
    float* out = (float*)d_out;               // quantized [65536*256] + loss [1]

    char* ws = (char*)d_ws;
    float* en = (float*)ws;                                           //    4096 B
    unsigned short* EbFH = (unsigned short*)(ws + 4096);              //  524288 B
    unsigned short* EbFL = (unsigned short*)(ws + 528384);            //  524288 B
    unsigned long long* packed = (unsigned long long*)(ws + 1052672); //  524288 B
    int* flagList1 = (int*)(ws + 1576960);                            //   65536 B
    int* flagList2 = (int*)(ws + 1642496);                            //   16384 B
    float* accum = (float*)(ws + 1658880);
    int* flagCnt = (int*)(ws + 1658884);                              // [cnt1, cnt2]

    vq_norms   <<<KC / 4, 256, 0, stream>>>(E, en, EbFH, EbFL, accum, flagCnt);
    vq_pass1   <<<NROWS / 128, 256, 0, stream>>>(X, EbFH, en, packed, flagCnt, flagList1);
    vq_pass2   <<<FCAP1 / 32, 256, 0, stream>>>(X, EbFH, EbFL, en, packed, flagCnt, flagList1, flagList2);
    vq_pass3   <<<64, 256, 0, stream>>>(X, E, en, packed, flagCnt + 1, flagList2);
    vq_gather  <<<NROWS / 16, 256, 0, stream>>>(X, E, packed, out, accum);
    vq_finalize<<<1, 1, 0, stream>>>(accum, out + (size_t)NROWS * DIM);
}